// Round 7
// baseline (1666.071 us; speedup 1.0000x reference)
//
#include <hip/hip_runtime.h>
#include <hip/hip_bf16.h>
#include <hip/hip_fp16.h>
#include <math.h>

#define Lq 512
#define CSd 256
#define CZd 128
#define Hd 8
#define CHd 32
#define PQd 4
#define PVd 8
#define CATd 1536
#define NPROJ 1152

typedef __attribute__((ext_vector_type(4))) float floatx4;
typedef __attribute__((ext_vector_type(8))) short shortx8;

// ---------------- ws layout (float offsets) ----------------
#define OFF_SC      0         // 131072
#define OFF_PB      393216    // 1048576 (half)
#define OFF_QN      2031616   // 4096
#define OFF_KN      2035712   // 4096
#define OFF_A16     2039808   // 2097152: first half = a16hi, second = a16lo
#define OFF_CAT     4136960   // 786432
#define OFF_S0      4923392   // 131072 (also ipab alias; disjoint lifetimes)
#define OFF_R       5054464   // 4608
#define OFF_T       5059072   // 1536
#define OFF_GAMMA   5060608   // 8
#define OFF_MASKB   5060616   // 512
#define OFF_BCAT    5061128   // 1152
#define OFF_WINITP  5062280   // 65536
#define OFF_WT1P    5127816   // 65536
#define OFF_WT2P    5193352   // 65536
#define OFF_WT3P    5258888   // 65536
#define OFF_WOP     5324424   // 393216
#define OFF_WCATP   5717640   // 294912
#define OFF_QP      6012552   // 262144 (fp32)
#define OFF_KP      6274696   // 262144 (=524288 bf16)
#define OFF_VP      6536840   // 262144 (=524288 bf16)
#define OFF_ZNT     6798984   // 16777216 (=33554432 bf16)  [i][c][j]

#define WLC 0.57735026918962576f
#define WCC 0.23570226039551584f
#define ISC 0.17677669529663687f

__device__ __forceinline__ float wave_sum(float v){
  #pragma unroll
  for (int m=32; m; m>>=1) v += __shfl_xor(v, m);
  return v;
}
__device__ __forceinline__ short f2bf(float v){
  __hip_bfloat16 h = (__hip_bfloat16)v;
  return __builtin_bit_cast(short, h);
}
__device__ __forceinline__ float bf2f(short s){
  unsigned u = ((unsigned)(unsigned short)s) << 16;
  return __builtin_bit_cast(float, u);
}
__device__ __forceinline__ __hip_bfloat16 s2b(short s){
  return __builtin_bit_cast(__hip_bfloat16, s);
}

// ------------- setup -------------
__global__ __launch_bounds__(256) void k_setup(
    const float* __restrict__ bq, const float* __restrict__ bk, const float* __restrict__ bv,
    const float* __restrict__ bqp, const float* __restrict__ bkp, const float* __restrict__ bvp,
    const float* __restrict__ head_w, const float* __restrict__ mask,
    float* __restrict__ bcat, float* __restrict__ gamma,
    float* __restrict__ maskb, float* __restrict__ R, float* __restrict__ t){
  int k = blockIdx.x*256 + threadIdx.x;
  if (k < NPROJ){
    float v;
    if      (k < 256) v = bq[k];
    else if (k < 512) v = bk[k-256];
    else if (k < 768) v = bv[k-512];
    else if (k < 864) v = bqp[k-768];
    else if (k < 960) v = bkp[k-864];
    else              v = bvp[k-960];
    bcat[k] = v;
    return;
  }
  k -= NPROJ;
  if (k < Hd){ gamma[k] = log1pf(expf(head_w[k])); return; }
  k -= Hd;
  if (k < Lq){ maskb[k] = (mask[k] - 1.f)*1e9f; return; }
  k -= Lq;
  if (k < Lq){
    #pragma unroll
    for (int ii=0; ii<9; ii++) R[k*9+ii] = (ii==0||ii==4||ii==8) ? 1.f : 0.f;
    t[k*3] = 0.f; t[k*3+1] = 0.f; t[k*3+2] = 0.f;
  }
}

// ------------- pack [K,N] fp32 weight into MFMA-B hi/lo bf16 layout -------------
__global__ __launch_bounds__(256) void k_pack(
    const float* __restrict__ W, int K, int N, __hip_bfloat16* __restrict__ out){
  int idx = blockIdx.x*256 + threadIdx.x;
  if (idx >= K*N) return;
  int j = idx & 7, lane = (idx>>3) & 63, rest = idx >> 9;
  int nt = N >> 4;
  int tn = rest % nt, tk = rest / nt;
  int k = tk*32 + (lane>>4)*8 + j;
  int n = tn*16 + (lane&15);
  float v = W[(size_t)k*N + n];
  short h = f2bf(v);
  short l = f2bf(v - bf2f(h));
  size_t base = (size_t)rest*1024 + (idx & 511);
  out[base]       = s2b(h);
  out[base + 512] = s2b(l);
}

// ------------- batched pack for four 256x256 weights -------------
__global__ __launch_bounds__(256) void k_pack4(
    const float* __restrict__ W0, const float* __restrict__ W1,
    const float* __restrict__ W2, const float* __restrict__ W3,
    __hip_bfloat16* __restrict__ O0, __hip_bfloat16* __restrict__ O1,
    __hip_bfloat16* __restrict__ O2, __hip_bfloat16* __restrict__ O3){
  const float* Ws[4] = {W0,W1,W2,W3};
  __hip_bfloat16* Os[4] = {O0,O1,O2,O3};
  const float* W = Ws[blockIdx.y];
  __hip_bfloat16* out = Os[blockIdx.y];
  int idx = blockIdx.x*256 + threadIdx.x;
  int j = idx & 7, lane = (idx>>3) & 63, rest = idx >> 9;
  int tn = rest % 16, tk = rest / 16;
  int k = tk*32 + (lane>>4)*8 + j;
  int n = tn*16 + (lane&15);
  float v = W[(size_t)k*256 + n];
  short h = f2bf(v);
  short l = f2bf(v - bf2f(h));
  size_t base = (size_t)rest*1024 + (idx & 511);
  out[base]       = s2b(h);
  out[base + 512] = s2b(l);
}

// ------------- pack concatenated projection weight (virtual [256,1152]) -------------
__global__ __launch_bounds__(256) void k_pack_cat(
    const float* __restrict__ wq, const float* __restrict__ wk, const float* __restrict__ wv,
    const float* __restrict__ wqp, const float* __restrict__ wkp, const float* __restrict__ wvp,
    __hip_bfloat16* __restrict__ out){
  int idx = blockIdx.x*256 + threadIdx.x;
  if (idx >= CSd*NPROJ) return;
  int j = idx & 7, lane = (idx>>3) & 63, rest = idx >> 9;
  const int nt = NPROJ >> 4;
  int tn = rest % nt, tk = rest / nt;
  int k = tk*32 + (lane>>4)*8 + j;
  int n = tn*16 + (lane&15);
  float v;
  if      (n < 256) v = wq[k*256 + n];
  else if (n < 512) v = wk[k*256 + n-256];
  else if (n < 768) v = wv[k*256 + n-512];
  else if (n < 864) v = wqp[k*96 + n-768];
  else if (n < 960) v = wkp[k*96 + n-864];
  else              v = wvp[k*192 + n-960];
  short h = f2bf(v);
  short l = f2bf(v - bf2f(h));
  size_t base = (size_t)rest*1024 + (idx & 511);
  out[base]       = s2b(h);
  out[base + 512] = s2b(l);
}

// ------------- split-precision MFMA GEMM -------------
__global__ __launch_bounds__(256) void k_gemm_mfma(
    const float* __restrict__ A, int K,
    const __hip_bfloat16* __restrict__ Bp, int N,
    const float* __restrict__ bias,
    float* __restrict__ Cf,
    int relu, const float* __restrict__ rowscale){
  int tid = threadIdx.x;
  int wave = tid>>6, lane = tid&63;
  int i0 = blockIdx.y*64 + wave*16;
  int n0 = blockIdx.x*64;
  int quad = lane>>4, l16 = lane&15;
  floatx4 acc[4] = {};
  const int ntiles = N >> 4;
  const float* arow = A + (size_t)(i0 + l16)*K + quad*8;
  const __hip_bfloat16* bbase = Bp + ((size_t)(n0>>4))*1024 + (size_t)(lane&63)*8;
  for (int k0=0; k0<K; k0+=32){
    float4 v0 = *(const float4*)(arow + k0);
    float4 v1 = *(const float4*)(arow + k0 + 4);
    float av[8] = {v0.x,v0.y,v0.z,v0.w,v1.x,v1.y,v1.z,v1.w};
    shortx8 ahi, alo;
    #pragma unroll
    for (int j=0; j<8; j++){
      short h = f2bf(av[j]);
      ahi[j] = h;
      alo[j] = f2bf(av[j] - bf2f(h));
    }
    const __hip_bfloat16* bt = bbase + (size_t)(k0>>5)*ntiles*1024;
    #pragma unroll
    for (int s=0; s<4; s++){
      shortx8 bhi = *(const shortx8*)(bt + s*1024);
      shortx8 blo = *(const shortx8*)(bt + s*1024 + 512);
      acc[s] = __builtin_amdgcn_mfma_f32_16x16x32_bf16(ahi, bhi, acc[s], 0, 0, 0);
      acc[s] = __builtin_amdgcn_mfma_f32_16x16x32_bf16(alo, bhi, acc[s], 0, 0, 0);
      acc[s] = __builtin_amdgcn_mfma_f32_16x16x32_bf16(ahi, blo, acc[s], 0, 0, 0);
    }
  }
  #pragma unroll
  for (int s=0; s<4; s++){
    int n = n0 + s*16 + l16;
    float bs = bias ? bias[n] : 0.f;
    #pragma unroll
    for (int r=0; r<4; r++){
      int m = i0 + quad*4 + r;
      float v = acc[s][r] + bs;
      if (relu) v = fmaxf(v, 0.f);
      if (rowscale) v *= rowscale[m];
      Cf[(size_t)m*N + n] = v;
    }
  }
}

// ------------- LN over CS=256 row -------------
__global__ __launch_bounds__(256) void k_addln(
    const float* __restrict__ x, const float* __restrict__ y,
    const float* __restrict__ g, const float* __restrict__ b,
    float* __restrict__ out){
  __shared__ float red[4];
  int row = blockIdx.x, tid = threadIdx.x;
  float v = x[row*CSd + tid];
  if (y) v += y[row*CSd + tid];
  int wid = tid>>6, lane = tid&63;
  float s = wave_sum(v);
  if (lane==0) red[wid] = s;
  __syncthreads();
  float mu = (red[0]+red[1]+red[2]+red[3]) * (1.f/CSd);
  __syncthreads();
  float d = v - mu;
  float s2 = wave_sum(d*d);
  if (lane==0) red[wid] = s2;
  __syncthreads();
  float var = (red[0]+red[1]+red[2]+red[3]) * (1.f/CSd);
  float rs = rsqrtf(var + 1e-5f);
  out[row*CSd + tid] = d*rs*g[tid] + b[tid];
}

// ------------- zn LN: pair_bias (half) + znt bf16 [i][c][j] -------------
__global__ __launch_bounds__(256) void k_lnz_pb(
    const float* __restrict__ z, const float* __restrict__ g, const float* __restrict__ b,
    const float* __restrict__ wpb, __half* __restrict__ pb, __hip_bfloat16* __restrict__ znt){
  __shared__ float Zt[64*129];
  __shared__ float gwt[8][132];
  __shared__ float AB[16];
  __shared__ float red[64*4*11];
  __shared__ float mvl[64][2];
  int tid = threadIdx.x;
  size_t row0 = (size_t)blockIdx.x*64;
  int ib = (int)(row0 >> 9), j0 = (int)(row0 & 511);
  const float4* zsrc = (const float4*)(z + row0*CZd);
  #pragma unroll
  for (int it=0; it<8; it++){
    int idx = tid + it*256;
    int rr = idx>>5, qq = idx&31;
    float4 v = zsrc[idx];
    float* dst = &Zt[rr*129 + qq*4];
    dst[0]=v.x; dst[1]=v.y; dst[2]=v.z; dst[3]=v.w;
  }
  for (int idx=tid; idx<1024; idx+=256){
    int h = idx&7, c = idx>>3;
    gwt[h][c] = g[c]*wpb[c*8+h];
  }
  if (tid < 16){
    int h = tid&7; const float* src = (tid<8) ? g : b;
    float s = 0.f;
    for (int c=0; c<128; c++) s += src[c]*wpb[c*8+h];
    AB[tid] = s;
  }
  __syncthreads();
  int q = tid>>6, r = tid&63;
  const float* zr = &Zt[r*129 + q*32];
  float zv[32];
  #pragma unroll
  for (int t=0; t<32; t++) zv[t] = zr[t];
  float S1=0.f, S2=0.f;
  #pragma unroll
  for (int t=0; t<32; t++){ S1 += zv[t]; S2 += zv[t]*zv[t]; }
  float* rd = &red[(r*4+q)*11];
  rd[8]=S1; rd[9]=S2;
  #pragma unroll
  for (int h=0; h<8; h++){
    const float4* gw4 = (const float4*)&gwt[h][q*32];
    float d = 0.f;
    #pragma unroll
    for (int t4=0; t4<8; t4++){
      float4 gv = gw4[t4];
      d += zv[t4*4]*gv.x + zv[t4*4+1]*gv.y + zv[t4*4+2]*gv.z + zv[t4*4+3]*gv.w;
    }
    rd[h] = d;
  }
  __syncthreads();
  if (tid < 64){
    int rr = tid;
    const float* r0 = &red[rr*44];
    float acc[10];
    #pragma unroll
    for (int v=0; v<10; v++) acc[v] = r0[v] + r0[11+v] + r0[22+v] + r0[33+v];
    float mu  = acc[8]*(1.f/128.f);
    float var = acc[9]*(1.f/128.f) - mu*mu;
    float rs  = rsqrtf(var + 1e-5f);
    mvl[rr][0] = mu; mvl[rr][1] = rs;
    int j = j0 + rr;
    #pragma unroll
    for (int h=0; h<8; h++){
      float pbv = rs*(acc[h] - mu*AB[h]) + AB[8+h];
      pb[((size_t)(h*Lq+ib))*Lq + j] = __float2half(pbv);
    }
  }
  __syncthreads();
  #pragma unroll
  for (int it2=0; it2<32; it2++){
    int idx = it2*256 + tid;
    int c = idx >> 6, jo = idx & 63;
    float mu = mvl[jo][0], rs = mvl[jo][1];
    float zn = (Zt[jo*129 + c] - mu)*rs*g[c] + b[c];
    znt[((size_t)ib*128 + c)*512 + j0 + jo] = (__hip_bfloat16)zn;
  }
}

// ------------- pack Q'/K'/V' in MFMA layouts, compute qn/kn -------------
__global__ __launch_bounds__(256) void k_packqkv(
    const float* __restrict__ P, const float* __restrict__ R, const float* __restrict__ t,
    const float* __restrict__ gamma,
    float* __restrict__ Qp, __hip_bfloat16* __restrict__ Kp, __hip_bfloat16* __restrict__ Vp,
    float* __restrict__ qn, float* __restrict__ kn){
  int idx = blockIdx.x*256 + threadIdx.x;   // 3*262144
  int region = idx >> 18;
  int rem = idx & 262143;
  int h = rem >> 15;
  int r2 = rem & 32767;
  if (region == 0){
    int j = r2 >> 6, f = r2 & 63;
    float val = 0.f;
    if (f < 32) val = P[(size_t)j*NPROJ + 256 + h*CHd + f];
    else if (f < 44){
      int p = (f-32)/3, ax = (f-32)%3;
      const float* kp = P + (size_t)j*NPROJ + 864 + h*12 + p*3;
      const float* Rr = R + j*9 + ax*3;
      val = Rr[0]*kp[0] + Rr[1]*kp[1] + Rr[2]*kp[2] + t[j*3+ax];
    }
    short hi = f2bf(val), lo = f2bf(val - bf2f(hi));
    int kc = f>>5, jt = j>>4, l16 = j&15, fl = f&31, quad = fl>>3, jj = f&7;
    size_t base = (size_t)((h*2+kc)*32 + jt)*1024 + (quad*16+l16)*8 + jj;
    Kp[base] = s2b(hi);
    Kp[base+512] = s2b(lo);
    if (f == 0){
      const float* Rm = R + j*9; const float* tv = t + j*3;
      float acc = 0.f;
      #pragma unroll
      for (int p=0; p<PQd; p++){
        const float* kp = P + (size_t)j*NPROJ + 864 + h*12 + p*3;
        #pragma unroll
        for (int ax=0; ax<3; ax++){
          float g = Rm[ax*3]*kp[0] + Rm[ax*3+1]*kp[1] + Rm[ax*3+2]*kp[2] + tv[ax];
          acc += g*g;
        }
      }
      kn[j*Hd + h] = acc;
    }
  } else if (region == 1){
    int j = r2 >> 6, n = r2 & 63;
    float val = 0.f;
    if (n < 32) val = P[(size_t)j*NPROJ + 512 + h*CHd + n];
    else if (n < 56){
      int p = (n-32)/3, ax = (n-32)%3;
      const float* vp = P + (size_t)j*NPROJ + 960 + h*24 + p*3;
      const float* Rr = R + j*9 + ax*3;
      val = Rr[0]*vp[0] + Rr[1]*vp[1] + Rr[2]*vp[2] + t[j*3+ax];
    }
    short hi = f2bf(val), lo = f2bf(val - bf2f(hi));
    int kc2 = j>>5, w = n>>4, l16 = n&15, jl = j&31, quad = jl>>3, jj = j&7;
    size_t base = (size_t)((h*16+kc2)*4 + w)*1024 + (quad*16+l16)*8 + jj;
    Vp[base] = s2b(hi);
    Vp[base+512] = s2b(lo);
  } else {
    int i = r2 >> 6, f = r2 & 63;
    float val = 0.f;
    if (f < 32) val = P[(size_t)i*NPROJ + h*CHd + f] * (WLC*ISC);
    else if (f < 44){
      int p = (f-32)/3, ax = (f-32)%3;
      const float* qp = P + (size_t)i*NPROJ + 768 + h*12 + p*3;
      const float* Rr = R + i*9 + ax*3;
      float g = Rr[0]*qp[0] + Rr[1]*qp[1] + Rr[2]*qp[2] + t[i*3+ax];
      val = g * (WLC*WCC*gamma[h]);
    }
    Qp[((size_t)h*512 + i)*64 + f] = val;
    if (f == 0){
      const float* Rm = R + i*9; const float* tv = t + i*3;
      float acc = 0.f;
      #pragma unroll
      for (int p=0; p<PQd; p++){
        const float* qp = P + (size_t)i*NPROJ + 768 + h*12 + p*3;
        #pragma unroll
        for (int ax=0; ax<3; ax++){
          float g = Rm[ax*3]*qp[0] + Rm[ax*3+1]*qp[1] + Rm[ax*3+2]*qp[2] + tv[ax];
          acc += g*g;
        }
      }
      qn[i*Hd + h] = acc;
    }
  }
}

// ------------- fused attention -------------
__global__ __launch_bounds__(256) void k_attn(
    const float* __restrict__ Qp, const __hip_bfloat16* __restrict__ Kp,
    const __hip_bfloat16* __restrict__ Vp,
    const float* __restrict__ qn, const float* __restrict__ kn,
    const __half* __restrict__ pb, const float* __restrict__ maskb,
    const float* __restrict__ gamma,
    const float* __restrict__ R, const float* __restrict__ t,
    __hip_bfloat16* __restrict__ a16hi, __hip_bfloat16* __restrict__ a16lo,
    float* __restrict__ cat){
  __shared__ float At[16][516];
  __shared__ float Ot[16][36];
  __shared__ float red1[16][16];
  __shared__ float red2[16][16];
  __shared__ float invL[16];
  __shared__ float qnL[16];
  int tid = threadIdx.x;
  int i0 = blockIdx.x*16, h = blockIdx.y;
  int wave = tid>>6, lane = tid&63, quad = lane>>4, l16 = lane&15;
  float gam = gamma[h];
  float coef = 0.5f*WLC*WCC*gam;
  if (tid < 16) qnL[tid] = qn[(i0+tid)*Hd + h];
  __syncthreads();
  // hoisted Q load + hi/lo split (fixed per wave across all jt)
  const float* qrow = Qp + ((size_t)h*512 + i0 + l16)*64 + quad*8;
  shortx8 qhi[2], qlo[2];
  #pragma unroll
  for (int kc=0; kc<2; kc++){
    float4 v0 = *(const float4*)(qrow + kc*32);
    float4 v1 = *(const float4*)(qrow + kc*32 + 4);
    float av[8] = {v0.x,v0.y,v0.z,v0.w,v1.x,v1.y,v1.z,v1.w};
    #pragma unroll
    for (int j=0; j<8; j++){
      short hh = f2bf(av[j]);
      qhi[kc][j] = hh; qlo[kc][j] = f2bf(av[j] - bf2f(hh));
    }
  }
  for (int it=0; it<8; it++){
    int jt = it*4 + wave;
    floatx4 acc = {};
    #pragma unroll
    for (int kc=0; kc<2; kc++){
      const __hip_bfloat16* bt = Kp + (size_t)((h*2+kc)*32 + jt)*1024 + lane*8;
      shortx8 bhi = *(const shortx8*)bt;
      shortx8 blo = *(const shortx8*)(bt + 512);
      acc = __builtin_amdgcn_mfma_f32_16x16x32_bf16(qhi[kc], bhi, acc, 0, 0, 0);
      acc = __builtin_amdgcn_mfma_f32_16x16x32_bf16(qlo[kc], bhi, acc, 0, 0, 0);
      acc = __builtin_amdgcn_mfma_f32_16x16x32_bf16(qhi[kc], blo, acc, 0, 0, 0);
    }
    int j = jt*16 + l16;
    float knj = kn[j*Hd + h];
    float mbj = maskb[j];
    #pragma unroll
    for (int r=0; r<4; r++){
      int i = quad*4 + r;
      float pbv = __half2float(pb[((size_t)(h*Lq) + i0 + i)*Lq + j]);
      At[i][j] = acc[r] + WLC*pbv + mbj - coef*(qnL[i] + knj);
    }
  }
  __syncthreads();
  int srow = tid>>4, sseg = tid&15;
  {
    float m = -1e30f;
    #pragma unroll 8
    for (int k2=0; k2<32; k2++) m = fmaxf(m, At[srow][sseg + k2*16]);
    red1[srow][sseg] = m;
  }
  __syncthreads();
  float mrow = red1[srow][0];
  #pragma unroll
  for (int c=1;c<16;c++) mrow = fmaxf(mrow, red1[srow][c]);
  {
    float ssum = 0.f;
    #pragma unroll 8
    for (int k2=0; k2<32; k2++){
      int cc = sseg + k2*16;
      float e = __expf(At[srow][cc]-mrow);
      At[srow][cc] = e; ssum += e;
    }
    red2[srow][sseg] = ssum;
  }
  __syncthreads();
  if (tid < 16){
    float s=0.f;
    #pragma unroll
    for (int c=0;c<16;c++) s += red2[tid][c];
    invL[tid] = 1.f/s;
  }
  __syncthreads();
  for (int idx2=tid; idx2<8192; idx2+=256){
    int rr = idx2>>9, cc = idx2&511;
    float v = At[rr][cc]*invL[rr];
    At[rr][cc] = v;
    short hv = f2bf(v);
    short lv = f2bf(v - bf2f(hv));
    size_t ai = (((size_t)(i0+rr)*16 + (cc>>5))*8 + h)*32 + (cc&31);
    a16hi[ai] = s2b(hv);
    a16lo[ai] = s2b(lv);
  }
  __syncthreads();
  floatx4 acc2 = {};
  for (int kc2=0; kc2<16; kc2++){
    const float* ar = &At[l16][kc2*32 + quad*8];
    float4 v0 = *(const float4*)ar;
    float4 v1 = *(const float4*)(ar+4);
    float av[8] = {v0.x,v0.y,v0.z,v0.w,v1.x,v1.y,v1.z,v1.w};
    shortx8 ahi, alo;
    #pragma unroll
    for (int j=0; j<8; j++){
      short hh = f2bf(av[j]);
      ahi[j] = hh; alo[j] = f2bf(av[j] - bf2f(hh));
    }
    const __hip_bfloat16* bt = Vp + (size_t)((h*16+kc2)*4 + wave)*1024 + lane*8;
    shortx8 bhi = *(const shortx8*)bt;
    shortx8 blo = *(const shortx8*)(bt + 512);
    acc2 = __builtin_amdgcn_mfma_f32_16x16x32_bf16(ahi, bhi, acc2, 0, 0, 0);
    acc2 = __builtin_amdgcn_mfma_f32_16x16x32_bf16(alo, bhi, acc2, 0, 0, 0);
    acc2 = __builtin_amdgcn_mfma_f32_16x16x32_bf16(ahi, blo, acc2, 0, 0, 0);
  }
  {
    int n = wave*16 + l16;
    #pragma unroll
    for (int r=0;r<4;r++){
      int i = quad*4+r;
      if (n < 32) cat[(size_t)(i0+i)*CATd + h*CHd + n] = acc2[r];
      else        Ot[i][n-32] = acc2[r];
    }
  }
  __syncthreads();
  if (tid < 128){
    int i = tid>>3, p = tid&7, gi = i0+i;
    float o0 = Ot[i][p*3], o1 = Ot[i][p*3+1], o2 = Ot[i][p*3+2];
    float d0 = o0 - t[gi*3], d1 = o1 - t[gi*3+1], d2 = o2 - t[gi*3+2];
    const float* Rm = R + gi*9;
    float l0 = Rm[0]*d0 + Rm[3]*d1 + Rm[6]*d2;
    float l1 = Rm[1]*d0 + Rm[4]*d1 + Rm[7]*d2;
    float l2 = Rm[2]*d0 + Rm[5]*d1 + Rm[8]*d2;
    float* cr = cat + (size_t)gi*CATd;
    cr[256 + h*24 + p*3]   = l0;
    cr[256 + h*24 + p*3+1] = l1;
    cr[256 + h*24 + p*3+2] = l2;
    cr[448 + h*8 + p] = sqrtf(l0*l0 + l1*l1 + l2*l2 + 1e-8f);
  }
}

// ------------- opair = a @ zn via MFMA -------------
__global__ __launch_bounds__(256) void k_opair_mfma(
    const __hip_bfloat16* __restrict__ a16hi, const __hip_bfloat16* __restrict__ a16lo,
    const __hip_bfloat16* __restrict__ znt, float* __restrict__ cat){
  int i = blockIdx.x;
  int tid = threadIdx.x;
  int wave = tid>>6, lane = tid&63, quad = lane>>4, l16 = lane&15;
  int nt0 = wave*2, nt1 = wave*2+1;
  floatx4 acc0 = {}, acc1 = {};
  const __hip_bfloat16* abase_h = a16hi + ((size_t)i*16*8 + (l16&7))*32 + quad*8;
  const __hip_bfloat16* abase_l = a16lo + ((size_t)i*16*8 + (l16&7))*32 + quad*8;
  const __hip_bfloat16* zb0 = znt + ((size_t)i*128 + nt0*16 + l16)*512 + quad*8;
  const __hip_bfloat16* zb1 = znt + ((size_t)i*128 + nt1*16 + l16)*512 + quad*8;
  #pragma unroll
  for (int kt=0; kt<16; kt++){
    shortx8 ah = *(const shortx8*)(abase_h + kt*256);
    shortx8 al = *(const shortx8*)(abase_l + kt*256);
    shortx8 b0 = *(const shortx8*)(zb0 + kt*32);
    shortx8 b1 = *(const shortx8*)(zb1 + kt*32);
    acc0 = __builtin_amdgcn_mfma_f32_16x16x32_bf16(ah, b0, acc0, 0, 0, 0);
    acc0 = __builtin_amdgcn_mfma_f32_16x16x32_bf16(al, b0, acc0, 0, 0, 0);
    acc1 = __builtin_amdgcn_mfma_f32_16x16x32_bf16(ah, b1, acc1, 0, 0, 0);
    acc1 = __builtin_amdgcn_mfma_f32_16x16x32_bf16(al, b1, acc1, 0, 0, 0);
  }
  if (quad < 2){
    float* cr = cat + (size_t)i*CATd + 512;
    #pragma unroll
    for (int r=0; r<4; r++){
      int h = quad*4 + r;
      cr[h*CZd + nt0*16 + l16] = acc0[r];
      cr[h*CZd + nt1*16 + l16] = acc1[r];
    }
  }
}

// ------------- mega transition (no Wo phase) -------------
__device__ __forceinline__ void gemm_stage(
    const float (*X)[260], float (*Y)[260],
    const __hip_bfloat16* __restrict__ Wp, const float* __restrict__ bias,
    bool relu, int tid){
  int wave = tid>>6, lane = tid&63, quad = lane>>4, l16 = lane&15;
  floatx4 acc[4] = {};
  for (int kc=0; kc<8; kc++){
    const float* xr = &X[l16][kc*32 + quad*8];
    float4 v0 = *(const float4*)xr;
    float4 v1 = *(const float4*)(xr+4);
    float av[8] = {v0.x,v0.y,v0.z,v0.w,v1.x,v1.y,v1.z,v1.w};
    shortx8 ahi, alo;
    #pragma unroll
    for (int j=0; j<8; j++){
      short hh = f2bf(av[j]);
      ahi[j] = hh; alo[j] = f2bf(av[j] - bf2f(hh));
    }
    #pragma unroll
    for (int ns=0; ns<4; ns++){
      const __hip_bfloat16* bt = Wp + (size_t)(kc*16 + wave*4 + ns)*1024 + lane*8;
      shortx8 bhi = *(const shortx8*)bt;
      shortx8 blo = *(const shortx8*)(bt + 512);
      acc[ns] = __builtin_amdgcn_mfma_f32_16x16x32_bf16(ahi, bhi, acc[ns], 0, 0, 0);
      acc[ns] = __builtin_amdgcn_mfma_f32_16x16x32_bf16(alo, bhi, acc[ns], 0, 0, 0);
      acc[ns] = __builtin_amdgcn_mfma_f32_16x16x32_bf16(ahi, blo, acc[ns], 0, 0, 0);
    }
  }
  #pragma unroll
  for (int ns=0; ns<4; ns++){
    int n = wave*64 + ns*16 + l16;
    float bs = bias[n];
    #pragma unroll
    for (int r=0;r<4;r++){
      float v = acc[ns][r] + bs;
      if (relu) v = fmaxf(v, 0.f);
      Y[quad*4+r][n] = v;
    }
  }
}

__global__ __launch_bounds__(256) void k_mega(
    float* __restrict__ scb, const float* __restrict__ ipab,
    const float* __restrict__ gi_, const float* __restrict__ bi_,
    const __hip_bfloat16* __restrict__ W1, const float* __restrict__ c1,
    const __hip_bfloat16* __restrict__ W2, const float* __restrict__ c2,
    const __hip_bfloat16* __restrict__ W3, const float* __restrict__ c3,
    const float* __restrict__ gt_, const float* __restrict__ bt_,
    const float* __restrict__ mask,
    const float* __restrict__ wbb, const float* __restrict__ bbb,
    float* __restrict__ R, float* __restrict__ t){
  __shared__ float As[16][260], Bs[16][260], Cs[16][260];
  __shared__ float rA[16][17], rB[16][17];
  __shared__ float mv[16][2];
  __shared__ float u6p[16][6][2];
  int tid = threadIdx.x;
  int i0 = blockIdx.x*16;
  int r = tid>>4, c0 = (tid&15)*16;
  float v[16];
  {
    const float* sr = scb  + (size_t)(i0+r)*CSd + c0;
    const float* ir = ipab + (size_t)(i0+r)*CSd + c0;
    float s1=0.f, s2=0.f;
    #pragma unroll
    for (int k2=0;k2<16;k2++){ float x = sr[k2]+ir[k2]; v[k2]=x; s1+=x; s2+=x*x; }
    rA[r][tid&15]=s1; rB[r][tid&15]=s2;
  }
  __syncthreads();
  if (tid<16){
    float s1=0.f,s2=0.f;
    #pragma unroll
    for (int c=0;c<16;c++){ s1+=rA[tid][c]; s2+=rB[tid][c]; }
    float mu = s1*(1.f/CSd), var = s2*(1.f/CSd) - mu*mu;
    mv[tid][0]=mu; mv[tid][1]=rsqrtf(var+1e-5f);
  }
  __syncthreads();
  {
    float mu=mv[r][0], rs=mv[r][1];
    #pragma unroll
    for (int k2=0;k2<16;k2++) As[r][c0+k2] = (v[k2]-mu)*rs*gi_[c0+k2] + bi_[c0+k2];
  }
  __syncthreads();
  gemm_stage(As, Bs, W1, c1, true, tid);
  __syncthreads();
  gemm_stage(Bs, Cs, W2, c2, true, tid);
  __syncthreads();
  gemm_stage(Cs, Bs, W3, c3, false, tid);
  __syncthreads();
  {
    float mk = mask[i0+r];
    float s1=0.f, s2=0.f;
    #pragma unroll
    for (int k2=0;k2<16;k2++){ float x = As[r][c0+k2] + Bs[r][c0+k2]*mk; v[k2]=x; s1+=x; s2+=x*x; }
    rA[r][tid&15]=s1; rB[r][tid&15]=s2;
  }
  __syncthreads();
  if (tid<16){
    float s1=0.f,s2=0.f;
    #pragma unroll
    for (int c=0;c<16;c++){ s1+=rA[tid][c]; s2+=rB[tid][c]; }
    float mu = s1*(1.f/CSd), var = s2*(1.f/CSd) - mu*mu;
    mv[tid][0]=mu; mv[tid][1]=rsqrtf(var+1e-5f);
  }
  __syncthreads();
  {
    float mu=mv[r][0], rs=mv[r][1];
    float* out = scb + (size_t)(i0+r)*CSd + c0;
    #pragma unroll
    for (int k2=0;k2<16;k2++){
      float o = (v[k2]-mu)*rs*gt_[c0+k2] + bt_[c0+k2];
      As[r][c0+k2] = o;
      out[k2] = o;
    }
  }
  __syncthreads();
  if (tid < 192){
    int rr = tid/12, o = (tid%12)>>1, half = tid&1;
    float acc = half ? 0.f : bbb[o];
    int kb = half*128;
    for (int k2=kb; k2<kb+128; k2++) acc += As[rr][k2]*wbb[k2*6+o];
    u6p[rr][o][half] = acc;
  }
  __syncthreads();
  if (tid < 16){
    int gidx = i0 + tid;
    float uu[6];
    #pragma unroll
    for (int o=0;o<6;o++) uu[o] = u6p[tid][o][0] + u6p[tid][o][1];
    float bq = uu[0], cq = uu[1], dq = uu[2];
    float norm = sqrtf(1.f + bq*bq + cq*cq + dq*dq);
    float a = 1.f/norm, b_ = bq/norm, c_ = cq/norm, d_ = dq/norm;
    float dR[9];
    dR[0] = a*a + b_*b_ - c_*c_ - d_*d_; dR[1] = 2.f*(b_*c_ - a*d_); dR[2] = 2.f*(b_*d_ + a*c_);
    dR[3] = 2.f*(b_*c_ + a*d_); dR[4] = a*a - b_*b_ + c_*c_ - d_*d_; dR[5] = 2.f*(c_*d_ - a*b_);
    dR[6] = 2.f*(b_*d_ - a*c_); dR[7] = 2.f*(c_*d_ + a*b_); dR[8] = a*a - b_*b_ - c_*c_ + d_*d_;
    float mk = mask[gidx];
    float dt0 = uu[3]*mk, dt1 = uu[4]*mk, dt2 = uu[5]*mk;
    float Rm[9];
    #pragma unroll
    for (int ii=0; ii<9; ii++) Rm[ii] = R[gidx*9+ii];
    t[gidx*3]   += Rm[0]*dt0 + Rm[1]*dt1 + Rm[2]*dt2;
    t[gidx*3+1] += Rm[3]*dt0 + Rm[4]*dt1 + Rm[5]*dt2;
    t[gidx*3+2] += Rm[6]*dt0 + Rm[7]*dt1 + Rm[8]*dt2;
    #pragma unroll
    for (int ii=0; ii<3; ii++)
      #pragma unroll
      for (int jj=0; jj<3; jj++)
        R[gidx*9 + ii*3 + jj] = Rm[ii*3]*dR[jj] + Rm[ii*3+1]*dR[3+jj] + Rm[ii*3+2]*dR[6+jj];
  }
}

// ------------- final output write -------------
__global__ __launch_bounds__(256) void k_writeout(
    const float* __restrict__ sc, const float* __restrict__ R, const float* __restrict__ t,
    float* __restrict__ out){
  int idx = blockIdx.x*256 + threadIdx.x;
  if      (idx < 131072) out[idx] = sc[idx];
  else if (idx < 135680) out[idx] = R[idx-131072];
  else if (idx < 137216) out[idx] = t[idx-135680];
}

extern "C" void kernel_launch(void* const* d_in, const int* in_sizes, int n_in,
                              void* d_out, int out_size, void* d_ws, size_t ws_size,
                              hipStream_t stream){
  const float* s      = (const float*)d_in[0];
  const float* z      = (const float*)d_in[1];
  const float* mask   = (const float*)d_in[2];
  const float* ln_s_g = (const float*)d_in[3];
  const float* ln_s_b = (const float*)d_in[4];
  const float* ln_z_g = (const float*)d_in[5];
  const float* ln_z_b = (const float*)d_in[6];
  const float* w_init = (const float*)d_in[7];
  const float* b_init = (const float*)d_in[8];
  const float* ln_ipa_g = (const float*)d_in[9];
  const float* ln_ipa_b = (const float*)d_in[10];
  const float* ln_tr_g  = (const float*)d_in[11];
  const float* ln_tr_b  = (const float*)d_in[12];
  const float* wq = (const float*)d_in[13]; const float* bq = (const float*)d_in[14];
  const float* wk = (const float*)d_in[15]; const float* bk = (const float*)d_in[16];
  const float* wv = (const float*)d_in[17]; const float* bv = (const float*)d_in[18];
  const float* wqp = (const float*)d_in[19]; const float* bqp = (const float*)d_in[20];
  const float* wkp = (const float*)d_in[21]; const float* bkp = (const float*)d_in[22];
  const float* wvp = (const float*)d_in[23]; const float* bvp = (const float*)d_in[24];
  const float* wpb = (const float*)d_in[25];
  const float* head_w = (const float*)d_in[26];
  const float* wo = (const float*)d_in[27]; const float* bo = (const float*)d_in[28];
  const float* wt1 = (const float*)d_in[29]; const float* bt1 = (const float*)d_in[30];
  const float* wt2 = (const float*)d_in[31]; const float* bt2 = (const float*)d_in[32];
  const float* wt3 = (const float*)d_in[33]; const float* bt3 = (const float*)d_in[34];
  const float* wbb = (const float*)d_in[35]; const float* bbb = (const float*)d_in[36];

  float* W = (float*)d_ws;
  float* scb   = W + OFF_SC;
  __half*  pbb  = (__half*)(W + OFF_PB);
  float* qnb   = W + OFF_QN;
  float* knb   = W + OFF_KN;
  __hip_bfloat16* a16hi = (__hip_bfloat16*)(W + OFF_A16);
  __hip_bfloat16* a16lo = a16hi + 2097152;
  float* catb  = W + OFF_CAT;
  float* s0b   = W + OFF_S0;
  float* ipab  = W + OFF_S0;   // alias: s0 dead before loop
  float* Rb    = W + OFF_R;
  float* tb    = W + OFF_T;
  float* gammab= W + OFF_GAMMA;
  float* maskb = W + OFF_MASKB;
  float* bcat  = W + OFF_BCAT;
  __hip_bfloat16* WinitP = (__hip_bfloat16*)(W + OFF_WINITP);
  __hip_bfloat16* Wt1P   = (__hip_bfloat16*)(W + OFF_WT1P);
  __hip_bfloat16* Wt2P   = (__hip_bfloat16*)(W + OFF_WT2P);
  __hip_bfloat16* Wt3P   = (__hip_bfloat16*)(W + OFF_WT3P);
  __hip_bfloat16* WoP    = (__hip_bfloat16*)(W + OFF_WOP);
  __hip_bfloat16* WcatP  = (__hip_bfloat16*)(W + OFF_WCATP);
  float* Qp = W + OFF_QP;
  __hip_bfloat16* Kp = (__hip_bfloat16*)(W + OFF_KP);
  __hip_bfloat16* Vp = (__hip_bfloat16*)(W + OFF_VP);
  __hip_bfloat16* znt = (__hip_bfloat16*)(W + OFF_ZNT);

  k_setup<<<9, 256, 0, stream>>>(bq,bk,bv,bqp,bkp,bvp, head_w, mask, bcat, gammab, maskb, Rb, tb);
  k_pack_cat<<<CSd*NPROJ/256, 256, 0, stream>>>(wq,wk,wv,wqp,wkp,wvp, WcatP);
  k_pack4<<<dim3(256,4), 256, 0, stream>>>(w_init, wt1, wt2, wt3, WinitP, Wt1P, Wt2P, Wt3P);
  k_pack<<<1536, 256, 0, stream>>>(wo, CATd, CSd, WoP);

  k_addln<<<Lq, 256, 0, stream>>>(s, nullptr, ln_s_g, ln_s_b, s0b);
  k_gemm_mfma<<<dim3(4,8), 256, 0, stream>>>(s0b, CSd, WinitP, CSd, b_init, scb, 0, nullptr);
  k_lnz_pb<<<Lq*Lq/64, 256, 0, stream>>>(z, ln_z_g, ln_z_b, wpb, pbb, znt);

  for (int it=0; it<8; ++it){
    k_gemm_mfma<<<dim3(18,8), 256, 0, stream>>>(scb, CSd, WcatP, NPROJ, bcat, W + 1441792, 0, nullptr);
    k_packqkv<<<3072, 256, 0, stream>>>(W + 1441792, Rb, tb, gammab, Qp, Kp, Vp, qnb, knb);
    k_attn<<<dim3(32,8), 256, 0, stream>>>(Qp, Kp, Vp, qnb, knb, pbb, maskb, gammab, Rb, tb,
                                           a16hi, a16lo, catb);
    k_opair_mfma<<<Lq, 256, 0, stream>>>(a16hi, a16lo, znt, catb);
    k_gemm_mfma<<<dim3(4,8), 256, 0, stream>>>(catb, CATd, WoP, CSd, bo, ipab, 0, nullptr);
    k_mega<<<32, 256, 0, stream>>>(scb, ipab, ln_ipa_g, ln_ipa_b,
                                   Wt1P, bt1, Wt2P, bt2, Wt3P, bt3,
                                   ln_tr_g, ln_tr_b, mask, wbb, bbb, Rb, tb);
  }
  k_writeout<<<536, 256, 0, stream>>>(scb, Rb, tb, (float*)d_out);
}

// Round 8
// 1291.126 us; speedup vs baseline: 1.2904x; 1.2904x over previous
//
#include <hip/hip_runtime.h>
#include <hip/hip_bf16.h>
#include <hip/hip_fp16.h>
#include <math.h>

#define Lq 512
#define CSd 256
#define CZd 128
#define Hd 8
#define CHd 32
#define PQd 4
#define PVd 8
#define CATd 1536
#define NPROJ 1152

typedef __attribute__((ext_vector_type(4))) float floatx4;
typedef __attribute__((ext_vector_type(8))) short shortx8;

// ---------------- ws layout (float offsets) ----------------
#define OFF_SC      0         // 131072
#define OFF_PB      393216    // 1048576 (half)
#define OFF_P       1441792   // 589824
#define OFF_QN      2031616   // 4096
#define OFF_KN      2035712   // 4096
#define OFF_A16     2039808   // 2097152: first half = a16hi, second = a16lo
#define OFF_CAT     4136960   // 786432
#define OFF_S0      4923392   // 131072
#define OFF_R       5054464   // 4608
#define OFF_T       5059072   // 1536
#define OFF_GAMMA   5060608   // 8
#define OFF_MASKB   5060616   // 512
#define OFF_BCAT    5061128   // 1152
#define OFF_WINITP  5062280   // 65536
#define OFF_WT1P    5127816   // 65536
#define OFF_WT2P    5193352   // 65536
#define OFF_WT3P    5258888   // 65536
#define OFF_WOP     5324424   // 393216
#define OFF_WCATP   5717640   // 294912
#define OFF_QP      6012552   // 262144 (fp32)
#define OFF_KP      6274696   // 262144 (=524288 bf16)
#define OFF_VP      6536840   // 262144 (=524288 bf16)
#define OFF_ZNT     6798984   // 16777216 (=33554432 bf16)  [i][c][j]

#define WLC 0.57735026918962576f
#define WCC 0.23570226039551584f
#define ISC 0.17677669529663687f

__device__ __forceinline__ float wave_sum(float v){
  #pragma unroll
  for (int m=32; m; m>>=1) v += __shfl_xor(v, m);
  return v;
}
__device__ __forceinline__ short f2bf(float v){
  __hip_bfloat16 h = (__hip_bfloat16)v;
  return __builtin_bit_cast(short, h);
}
__device__ __forceinline__ float bf2f(short s){
  unsigned u = ((unsigned)(unsigned short)s) << 16;
  return __builtin_bit_cast(float, u);
}
__device__ __forceinline__ __hip_bfloat16 s2b(short s){
  return __builtin_bit_cast(__hip_bfloat16, s);
}

// ------------- setup -------------
__global__ __launch_bounds__(256) void k_setup(
    const float* __restrict__ bq, const float* __restrict__ bk, const float* __restrict__ bv,
    const float* __restrict__ bqp, const float* __restrict__ bkp, const float* __restrict__ bvp,
    const float* __restrict__ head_w, const float* __restrict__ mask,
    float* __restrict__ bcat, float* __restrict__ gamma,
    float* __restrict__ maskb, float* __restrict__ R, float* __restrict__ t){
  int k = blockIdx.x*256 + threadIdx.x;
  if (k < NPROJ){
    float v;
    if      (k < 256) v = bq[k];
    else if (k < 512) v = bk[k-256];
    else if (k < 768) v = bv[k-512];
    else if (k < 864) v = bqp[k-768];
    else if (k < 960) v = bkp[k-864];
    else              v = bvp[k-960];
    bcat[k] = v;
    return;
  }
  k -= NPROJ;
  if (k < Hd){ gamma[k] = log1pf(expf(head_w[k])); return; }
  k -= Hd;
  if (k < Lq){ maskb[k] = (mask[k] - 1.f)*1e9f; return; }
  k -= Lq;
  if (k < Lq){
    #pragma unroll
    for (int ii=0; ii<9; ii++) R[k*9+ii] = (ii==0||ii==4||ii==8) ? 1.f : 0.f;
    t[k*3] = 0.f; t[k*3+1] = 0.f; t[k*3+2] = 0.f;
  }
}

// ------------- pack [K,N] fp32 weight into MFMA-B hi/lo bf16 layout -------------
__global__ __launch_bounds__(256) void k_pack(
    const float* __restrict__ W, int K, int N, __hip_bfloat16* __restrict__ out){
  int idx = blockIdx.x*256 + threadIdx.x;
  if (idx >= K*N) return;
  int j = idx & 7, lane = (idx>>3) & 63, rest = idx >> 9;
  int nt = N >> 4;
  int tn = rest % nt, tk = rest / nt;
  int k = tk*32 + (lane>>4)*8 + j;
  int n = tn*16 + (lane&15);
  float v = W[(size_t)k*N + n];
  short h = f2bf(v);
  short l = f2bf(v - bf2f(h));
  size_t base = (size_t)rest*1024 + (idx & 511);
  out[base]       = s2b(h);
  out[base + 512] = s2b(l);
}

// ------------- pack concatenated projection weight (virtual [256,1152]) -------------
__global__ __launch_bounds__(256) void k_pack_cat(
    const float* __restrict__ wq, const float* __restrict__ wk, const float* __restrict__ wv,
    const float* __restrict__ wqp, const float* __restrict__ wkp, const float* __restrict__ wvp,
    __hip_bfloat16* __restrict__ out){
  int idx = blockIdx.x*256 + threadIdx.x;
  if (idx >= CSd*NPROJ) return;
  int j = idx & 7, lane = (idx>>3) & 63, rest = idx >> 9;
  const int nt = NPROJ >> 4;
  int tn = rest % nt, tk = rest / nt;
  int k = tk*32 + (lane>>4)*8 + j;
  int n = tn*16 + (lane&15);
  float v;
  if      (n < 256) v = wq[k*256 + n];
  else if (n < 512) v = wk[k*256 + n-256];
  else if (n < 768) v = wv[k*256 + n-512];
  else if (n < 864) v = wqp[k*96 + n-768];
  else if (n < 960) v = wkp[k*96 + n-864];
  else              v = wvp[k*192 + n-960];
  short h = f2bf(v);
  short l = f2bf(v - bf2f(h));
  size_t base = (size_t)rest*1024 + (idx & 511);
  out[base]       = s2b(h);
  out[base + 512] = s2b(l);
}

// ------------- split-precision MFMA GEMM -------------
__global__ __launch_bounds__(256) void k_gemm_mfma(
    const float* __restrict__ A, int K,
    const __hip_bfloat16* __restrict__ Bp, int N,
    const float* __restrict__ bias,
    float* __restrict__ Cf,
    int relu, const float* __restrict__ rowscale){
  int tid = threadIdx.x;
  int wave = tid>>6, lane = tid&63;
  int i0 = blockIdx.y*64 + wave*16;
  int n0 = blockIdx.x*64;
  int quad = lane>>4, l16 = lane&15;
  floatx4 acc[4] = {};
  const int ntiles = N >> 4;
  const float* arow = A + (size_t)(i0 + l16)*K + quad*8;
  const __hip_bfloat16* bbase = Bp + ((size_t)(n0>>4))*1024 + (size_t)(lane&63)*8;
  for (int k0=0; k0<K; k0+=32){
    float4 v0 = *(const float4*)(arow + k0);
    float4 v1 = *(const float4*)(arow + k0 + 4);
    float av[8] = {v0.x,v0.y,v0.z,v0.w,v1.x,v1.y,v1.z,v1.w};
    shortx8 ahi, alo;
    #pragma unroll
    for (int j=0; j<8; j++){
      short h = f2bf(av[j]);
      ahi[j] = h;
      alo[j] = f2bf(av[j] - bf2f(h));
    }
    const __hip_bfloat16* bt = bbase + (size_t)(k0>>5)*ntiles*1024;
    #pragma unroll
    for (int s=0; s<4; s++){
      shortx8 bhi = *(const shortx8*)(bt + s*1024);
      shortx8 blo = *(const shortx8*)(bt + s*1024 + 512);
      acc[s] = __builtin_amdgcn_mfma_f32_16x16x32_bf16(ahi, bhi, acc[s], 0, 0, 0);
      acc[s] = __builtin_amdgcn_mfma_f32_16x16x32_bf16(alo, bhi, acc[s], 0, 0, 0);
      acc[s] = __builtin_amdgcn_mfma_f32_16x16x32_bf16(ahi, blo, acc[s], 0, 0, 0);
    }
  }
  #pragma unroll
  for (int s=0; s<4; s++){
    int n = n0 + s*16 + l16;
    float bs = bias ? bias[n] : 0.f;
    #pragma unroll
    for (int r=0; r<4; r++){
      int m = i0 + quad*4 + r;
      float v = acc[s][r] + bs;
      if (relu) v = fmaxf(v, 0.f);
      if (rowscale) v *= rowscale[m];
      Cf[(size_t)m*N + n] = v;
    }
  }
}

// ------------- LN over CS=256 row -------------
__global__ __launch_bounds__(256) void k_addln(
    const float* __restrict__ x, const float* __restrict__ y,
    const float* __restrict__ g, const float* __restrict__ b,
    float* __restrict__ out){
  __shared__ float red[4];
  int row = blockIdx.x, tid = threadIdx.x;
  float v = x[row*CSd + tid];
  if (y) v += y[row*CSd + tid];
  int wid = tid>>6, lane = tid&63;
  float s = wave_sum(v);
  if (lane==0) red[wid] = s;
  __syncthreads();
  float mu = (red[0]+red[1]+red[2]+red[3]) * (1.f/CSd);
  __syncthreads();
  float d = v - mu;
  float s2 = wave_sum(d*d);
  if (lane==0) red[wid] = s2;
  __syncthreads();
  float var = (red[0]+red[1]+red[2]+red[3]) * (1.f/CSd);
  float rs = rsqrtf(var + 1e-5f);
  out[row*CSd + tid] = d*rs*g[tid] + b[tid];
}

// ------------- zn LN: pair_bias (half) + znt bf16 [i][c][j] -------------
__global__ __launch_bounds__(256) void k_lnz_pb(
    const float* __restrict__ z, const float* __restrict__ g, const float* __restrict__ b,
    const float* __restrict__ wpb, __half* __restrict__ pb, __hip_bfloat16* __restrict__ znt){
  __shared__ float Zt[64*129];
  __shared__ float gwt[8][132];
  __shared__ float AB[16];
  __shared__ float red[64*4*11];
  __shared__ float mvl[64][2];
  int tid = threadIdx.x;
  size_t row0 = (size_t)blockIdx.x*64;
  int ib = (int)(row0 >> 9), j0 = (int)(row0 & 511);
  const float4* zsrc = (const float4*)(z + row0*CZd);
  #pragma unroll
  for (int it=0; it<8; it++){
    int idx = tid + it*256;
    int rr = idx>>5, qq = idx&31;
    float4 v = zsrc[idx];
    float* dst = &Zt[rr*129 + qq*4];
    dst[0]=v.x; dst[1]=v.y; dst[2]=v.z; dst[3]=v.w;
  }
  for (int idx=tid; idx<1024; idx+=256){
    int h = idx&7, c = idx>>3;
    gwt[h][c] = g[c]*wpb[c*8+h];
  }
  if (tid < 16){
    int h = tid&7; const float* src = (tid<8) ? g : b;
    float s = 0.f;
    for (int c=0; c<128; c++) s += src[c]*wpb[c*8+h];
    AB[tid] = s;
  }
  __syncthreads();
  int q = tid>>6, r = tid&63;
  const float* zr = &Zt[r*129 + q*32];
  float zv[32];
  #pragma unroll
  for (int t=0; t<32; t++) zv[t] = zr[t];
  float S1=0.f, S2=0.f;
  #pragma unroll
  for (int t=0; t<32; t++){ S1 += zv[t]; S2 += zv[t]*zv[t]; }
  float* rd = &red[(r*4+q)*11];
  rd[8]=S1; rd[9]=S2;
  #pragma unroll
  for (int h=0; h<8; h++){
    const float4* gw4 = (const float4*)&gwt[h][q*32];
    float d = 0.f;
    #pragma unroll
    for (int t4=0; t4<8; t4++){
      float4 gv = gw4[t4];
      d += zv[t4*4]*gv.x + zv[t4*4+1]*gv.y + zv[t4*4+2]*gv.z + zv[t4*4+3]*gv.w;
    }
    rd[h] = d;
  }
  __syncthreads();
  if (tid < 64){
    int rr = tid;
    const float* r0 = &red[rr*44];
    float acc[10];
    #pragma unroll
    for (int v=0; v<10; v++) acc[v] = r0[v] + r0[11+v] + r0[22+v] + r0[33+v];
    float mu  = acc[8]*(1.f/128.f);
    float var = acc[9]*(1.f/128.f) - mu*mu;
    float rs  = rsqrtf(var + 1e-5f);
    mvl[rr][0] = mu; mvl[rr][1] = rs;
    int j = j0 + rr;
    #pragma unroll
    for (int h=0; h<8; h++){
      float pbv = rs*(acc[h] - mu*AB[h]) + AB[8+h];
      pb[((size_t)(h*Lq+ib))*Lq + j] = __float2half(pbv);
    }
  }
  __syncthreads();
  #pragma unroll
  for (int it2=0; it2<32; it2++){
    int idx = it2*256 + tid;
    int c = idx >> 6, jo = idx & 63;
    float mu = mvl[jo][0], rs = mvl[jo][1];
    float zn = (Zt[jo*129 + c] - mu)*rs*g[c] + b[c];
    znt[((size_t)ib*128 + c)*512 + j0 + jo] = (__hip_bfloat16)zn;
  }
}

// ------------- pack Q'/K'/V' in MFMA layouts, compute qn/kn -------------
__global__ __launch_bounds__(256) void k_packqkv(
    const float* __restrict__ P, const float* __restrict__ R, const float* __restrict__ t,
    const float* __restrict__ gamma,
    float* __restrict__ Qp, __hip_bfloat16* __restrict__ Kp, __hip_bfloat16* __restrict__ Vp,
    float* __restrict__ qn, float* __restrict__ kn){
  int idx = blockIdx.x*256 + threadIdx.x;   // 3*262144
  int region = idx >> 18;
  int rem = idx & 262143;
  int h = rem >> 15;
  int r2 = rem & 32767;
  if (region == 0){
    int j = r2 >> 6, f = r2 & 63;
    float val = 0.f;
    if (f < 32) val = P[(size_t)j*NPROJ + 256 + h*CHd + f];
    else if (f < 44){
      int p = (f-32)/3, ax = (f-32)%3;
      const float* kp = P + (size_t)j*NPROJ + 864 + h*12 + p*3;
      const float* Rr = R + j*9 + ax*3;
      val = Rr[0]*kp[0] + Rr[1]*kp[1] + Rr[2]*kp[2] + t[j*3+ax];
    }
    short hi = f2bf(val), lo = f2bf(val - bf2f(hi));
    int kc = f>>5, jt = j>>4, l16 = j&15, fl = f&31, quad = fl>>3, jj = f&7;
    size_t base = (size_t)((h*2+kc)*32 + jt)*1024 + (quad*16+l16)*8 + jj;
    Kp[base] = s2b(hi);
    Kp[base+512] = s2b(lo);
    if (f == 0){
      const float* Rm = R + j*9; const float* tv = t + j*3;
      float acc = 0.f;
      #pragma unroll
      for (int p=0; p<PQd; p++){
        const float* kp = P + (size_t)j*NPROJ + 864 + h*12 + p*3;
        #pragma unroll
        for (int ax=0; ax<3; ax++){
          float g = Rm[ax*3]*kp[0] + Rm[ax*3+1]*kp[1] + Rm[ax*3+2]*kp[2] + tv[ax];
          acc += g*g;
        }
      }
      kn[j*Hd + h] = acc;
    }
  } else if (region == 1){
    int j = r2 >> 6, n = r2 & 63;
    float val = 0.f;
    if (n < 32) val = P[(size_t)j*NPROJ + 512 + h*CHd + n];
    else if (n < 56){
      int p = (n-32)/3, ax = (n-32)%3;
      const float* vp = P + (size_t)j*NPROJ + 960 + h*24 + p*3;
      const float* Rr = R + j*9 + ax*3;
      val = Rr[0]*vp[0] + Rr[1]*vp[1] + Rr[2]*vp[2] + t[j*3+ax];
    }
    short hi = f2bf(val), lo = f2bf(val - bf2f(hi));
    int kc2 = j>>5, w = n>>4, l16 = n&15, jl = j&31, quad = jl>>3, jj = j&7;
    size_t base = (size_t)((h*16+kc2)*4 + w)*1024 + (quad*16+l16)*8 + jj;
    Vp[base] = s2b(hi);
    Vp[base+512] = s2b(lo);
  } else {
    int i = r2 >> 6, f = r2 & 63;
    float val = 0.f;
    if (f < 32) val = P[(size_t)i*NPROJ + h*CHd + f] * (WLC*ISC);
    else if (f < 44){
      int p = (f-32)/3, ax = (f-32)%3;
      const float* qp = P + (size_t)i*NPROJ + 768 + h*12 + p*3;
      const float* Rr = R + i*9 + ax*3;
      float g = Rr[0]*qp[0] + Rr[1]*qp[1] + Rr[2]*qp[2] + t[i*3+ax];
      val = g * (WLC*WCC*gamma[h]);
    }
    Qp[((size_t)h*512 + i)*64 + f] = val;
    if (f == 0){
      const float* Rm = R + i*9; const float* tv = t + i*3;
      float acc = 0.f;
      #pragma unroll
      for (int p=0; p<PQd; p++){
        const float* qp = P + (size_t)i*NPROJ + 768 + h*12 + p*3;
        #pragma unroll
        for (int ax=0; ax<3; ax++){
          float g = Rm[ax*3]*qp[0] + Rm[ax*3+1]*qp[1] + Rm[ax*3+2]*qp[2] + tv[ax];
          acc += g*g;
        }
      }
      qn[i*Hd + h] = acc;
    }
  }
}

// ------------- fused attention (Q split hoisted out of jt loop) -------------
__global__ __launch_bounds__(256) void k_attn(
    const float* __restrict__ Qp, const __hip_bfloat16* __restrict__ Kp,
    const __hip_bfloat16* __restrict__ Vp,
    const float* __restrict__ qn, const float* __restrict__ kn,
    const __half* __restrict__ pb, const float* __restrict__ maskb,
    const float* __restrict__ gamma,
    const float* __restrict__ R, const float* __restrict__ t,
    __hip_bfloat16* __restrict__ a16hi, __hip_bfloat16* __restrict__ a16lo,
    float* __restrict__ cat){
  __shared__ float At[16][516];
  __shared__ float Ot[16][36];
  __shared__ float red1[16][16];
  __shared__ float red2[16][16];
  __shared__ float invL[16];
  __shared__ float qnL[16];
  int tid = threadIdx.x;
  int i0 = blockIdx.x*16, h = blockIdx.y;
  int wave = tid>>6, lane = tid&63, quad = lane>>4, l16 = lane&15;
  float gam = gamma[h];
  float coef = 0.5f*WLC*WCC*gam;
  if (tid < 16) qnL[tid] = qn[(i0+tid)*Hd + h];
  __syncthreads();
  const float* qrow = Qp + ((size_t)h*512 + i0 + l16)*64 + quad*8;
  shortx8 qhi[2], qlo[2];
  #pragma unroll
  for (int kc=0; kc<2; kc++){
    float4 v0 = *(const float4*)(qrow + kc*32);
    float4 v1 = *(const float4*)(qrow + kc*32 + 4);
    float av[8] = {v0.x,v0.y,v0.z,v0.w,v1.x,v1.y,v1.z,v1.w};
    #pragma unroll
    for (int j=0; j<8; j++){
      short hh = f2bf(av[j]);
      qhi[kc][j] = hh; qlo[kc][j] = f2bf(av[j] - bf2f(hh));
    }
  }
  for (int it=0; it<8; it++){
    int jt = it*4 + wave;
    floatx4 acc = {};
    #pragma unroll
    for (int kc=0; kc<2; kc++){
      const __hip_bfloat16* bt = Kp + (size_t)((h*2+kc)*32 + jt)*1024 + lane*8;
      shortx8 bhi = *(const shortx8*)bt;
      shortx8 blo = *(const shortx8*)(bt + 512);
      acc = __builtin_amdgcn_mfma_f32_16x16x32_bf16(qhi[kc], bhi, acc, 0, 0, 0);
      acc = __builtin_amdgcn_mfma_f32_16x16x32_bf16(qlo[kc], bhi, acc, 0, 0, 0);
      acc = __builtin_amdgcn_mfma_f32_16x16x32_bf16(qhi[kc], blo, acc, 0, 0, 0);
    }
    int j = jt*16 + l16;
    float knj = kn[j*Hd + h];
    float mbj = maskb[j];
    #pragma unroll
    for (int r=0; r<4; r++){
      int i = quad*4 + r;
      float pbv = __half2float(pb[((size_t)(h*Lq) + i0 + i)*Lq + j]);
      At[i][j] = acc[r] + WLC*pbv + mbj - coef*(qnL[i] + knj);
    }
  }
  __syncthreads();
  int srow = tid>>4, sseg = tid&15;
  {
    float m = -1e30f;
    #pragma unroll 8
    for (int k2=0; k2<32; k2++) m = fmaxf(m, At[srow][sseg + k2*16]);
    red1[srow][sseg] = m;
  }
  __syncthreads();
  float mrow = red1[srow][0];
  #pragma unroll
  for (int c=1;c<16;c++) mrow = fmaxf(mrow, red1[srow][c]);
  {
    float ssum = 0.f;
    #pragma unroll 8
    for (int k2=0; k2<32; k2++){
      int cc = sseg + k2*16;
      float e = __expf(At[srow][cc]-mrow);
      At[srow][cc] = e; ssum += e;
    }
    red2[srow][sseg] = ssum;
  }
  __syncthreads();
  if (tid < 16){
    float s=0.f;
    #pragma unroll
    for (int c=0;c<16;c++) s += red2[tid][c];
    invL[tid] = 1.f/s;
  }
  __syncthreads();
  for (int idx2=tid; idx2<8192; idx2+=256){
    int rr = idx2>>9, cc = idx2&511;
    float v = At[rr][cc]*invL[rr];
    At[rr][cc] = v;
    short hv = f2bf(v);
    short lv = f2bf(v - bf2f(hv));
    size_t ai = (((size_t)(i0+rr)*16 + (cc>>5))*8 + h)*32 + (cc&31);
    a16hi[ai] = s2b(hv);
    a16lo[ai] = s2b(lv);
  }
  __syncthreads();
  floatx4 acc2 = {};
  for (int kc2=0; kc2<16; kc2++){
    const float* ar = &At[l16][kc2*32 + quad*8];
    float4 v0 = *(const float4*)ar;
    float4 v1 = *(const float4*)(ar+4);
    float av[8] = {v0.x,v0.y,v0.z,v0.w,v1.x,v1.y,v1.z,v1.w};
    shortx8 ahi, alo;
    #pragma unroll
    for (int j=0; j<8; j++){
      short hh = f2bf(av[j]);
      ahi[j] = hh; alo[j] = f2bf(av[j] - bf2f(hh));
    }
    const __hip_bfloat16* bt = Vp + (size_t)((h*16+kc2)*4 + wave)*1024 + lane*8;
    shortx8 bhi = *(const shortx8*)bt;
    shortx8 blo = *(const shortx8*)(bt + 512);
    acc2 = __builtin_amdgcn_mfma_f32_16x16x32_bf16(ahi, bhi, acc2, 0, 0, 0);
    acc2 = __builtin_amdgcn_mfma_f32_16x16x32_bf16(alo, bhi, acc2, 0, 0, 0);
    acc2 = __builtin_amdgcn_mfma_f32_16x16x32_bf16(ahi, blo, acc2, 0, 0, 0);
  }
  {
    int n = wave*16 + l16;
    #pragma unroll
    for (int r=0;r<4;r++){
      int i = quad*4+r;
      if (n < 32) cat[(size_t)(i0+i)*CATd + h*CHd + n] = acc2[r];
      else        Ot[i][n-32] = acc2[r];
    }
  }
  __syncthreads();
  if (tid < 128){
    int i = tid>>3, p = tid&7, gi = i0+i;
    float o0 = Ot[i][p*3], o1 = Ot[i][p*3+1], o2 = Ot[i][p*3+2];
    float d0 = o0 - t[gi*3], d1 = o1 - t[gi*3+1], d2 = o2 - t[gi*3+2];
    const float* Rm = R + gi*9;
    float l0 = Rm[0]*d0 + Rm[3]*d1 + Rm[6]*d2;
    float l1 = Rm[1]*d0 + Rm[4]*d1 + Rm[7]*d2;
    float l2 = Rm[2]*d0 + Rm[5]*d1 + Rm[8]*d2;
    float* cr = cat + (size_t)gi*CATd;
    cr[256 + h*24 + p*3]   = l0;
    cr[256 + h*24 + p*3+1] = l1;
    cr[256 + h*24 + p*3+2] = l2;
    cr[448 + h*8 + p] = sqrtf(l0*l0 + l1*l1 + l2*l2 + 1e-8f);
  }
}

// ------------- opair = a @ zn via MFMA -------------
__global__ __launch_bounds__(256) void k_opair_mfma(
    const __hip_bfloat16* __restrict__ a16hi, const __hip_bfloat16* __restrict__ a16lo,
    const __hip_bfloat16* __restrict__ znt, float* __restrict__ cat){
  int i = blockIdx.x;
  int tid = threadIdx.x;
  int wave = tid>>6, lane = tid&63, quad = lane>>4, l16 = lane&15;
  int nt0 = wave*2, nt1 = wave*2+1;
  floatx4 acc0 = {}, acc1 = {};
  const __hip_bfloat16* abase_h = a16hi + ((size_t)i*16*8 + (l16&7))*32 + quad*8;
  const __hip_bfloat16* abase_l = a16lo + ((size_t)i*16*8 + (l16&7))*32 + quad*8;
  const __hip_bfloat16* zb0 = znt + ((size_t)i*128 + nt0*16 + l16)*512 + quad*8;
  const __hip_bfloat16* zb1 = znt + ((size_t)i*128 + nt1*16 + l16)*512 + quad*8;
  #pragma unroll
  for (int kt=0; kt<16; kt++){
    shortx8 ah = *(const shortx8*)(abase_h + kt*256);
    shortx8 al = *(const shortx8*)(abase_l + kt*256);
    shortx8 b0 = *(const shortx8*)(zb0 + kt*32);
    shortx8 b1 = *(const shortx8*)(zb1 + kt*32);
    acc0 = __builtin_amdgcn_mfma_f32_16x16x32_bf16(ah, b0, acc0, 0, 0, 0);
    acc0 = __builtin_amdgcn_mfma_f32_16x16x32_bf16(al, b0, acc0, 0, 0, 0);
    acc1 = __builtin_amdgcn_mfma_f32_16x16x32_bf16(ah, b1, acc1, 0, 0, 0);
    acc1 = __builtin_amdgcn_mfma_f32_16x16x32_bf16(al, b1, acc1, 0, 0, 0);
  }
  if (quad < 2){
    float* cr = cat + (size_t)i*CATd + 512;
    #pragma unroll
    for (int r=0; r<4; r++){
      int h = quad*4 + r;
      cr[h*CZd + nt0*16 + l16] = acc0[r];
      cr[h*CZd + nt1*16 + l16] = acc1[r];
    }
  }
}

// ------------- mega: wo-GEMM + LN + 3 GEMMs + LN + upd + frame update -------------
__device__ __forceinline__ void gemm_stage(
    const float (*X)[260], float (*Y)[260],
    const __hip_bfloat16* __restrict__ Wp, const float* __restrict__ bias,
    bool relu, int tid){
  int wave = tid>>6, lane = tid&63, quad = lane>>4, l16 = lane&15;
  floatx4 acc[4] = {};
  for (int kc=0; kc<8; kc++){
    const float* xr = &X[l16][kc*32 + quad*8];
    float4 v0 = *(const float4*)xr;
    float4 v1 = *(const float4*)(xr+4);
    float av[8] = {v0.x,v0.y,v0.z,v0.w,v1.x,v1.y,v1.z,v1.w};
    shortx8 ahi, alo;
    #pragma unroll
    for (int j=0; j<8; j++){
      short hh = f2bf(av[j]);
      ahi[j] = hh; alo[j] = f2bf(av[j] - bf2f(hh));
    }
    #pragma unroll
    for (int ns=0; ns<4; ns++){
      const __hip_bfloat16* bt = Wp + (size_t)(kc*16 + wave*4 + ns)*1024 + lane*8;
      shortx8 bhi = *(const shortx8*)bt;
      shortx8 blo = *(const shortx8*)(bt + 512);
      acc[ns] = __builtin_amdgcn_mfma_f32_16x16x32_bf16(ahi, bhi, acc[ns], 0, 0, 0);
      acc[ns] = __builtin_amdgcn_mfma_f32_16x16x32_bf16(alo, bhi, acc[ns], 0, 0, 0);
      acc[ns] = __builtin_amdgcn_mfma_f32_16x16x32_bf16(ahi, blo, acc[ns], 0, 0, 0);
    }
  }
  #pragma unroll
  for (int ns=0; ns<4; ns++){
    int n = wave*64 + ns*16 + l16;
    float bs = bias[n];
    #pragma unroll
    for (int r=0;r<4;r++){
      float v = acc[ns][r] + bs;
      if (relu) v = fmaxf(v, 0.f);
      Y[quad*4+r][n] = v;
    }
  }
}

__global__ __launch_bounds__(256) void k_mega(
    float* __restrict__ scb, const float* __restrict__ cat,
    const __hip_bfloat16* __restrict__ Wo, const float* __restrict__ bo,
    const float* __restrict__ gi_, const float* __restrict__ bi_,
    const __hip_bfloat16* __restrict__ W1, const float* __restrict__ c1,
    const __hip_bfloat16* __restrict__ W2, const float* __restrict__ c2,
    const __hip_bfloat16* __restrict__ W3, const float* __restrict__ c3,
    const float* __restrict__ gt_, const float* __restrict__ bt_,
    const float* __restrict__ mask,
    const float* __restrict__ wbb, const float* __restrict__ bbb,
    float* __restrict__ R, float* __restrict__ t){
  __shared__ float As[16][260], Bs[16][260], Cs[16][260];
  __shared__ float rA[16][17], rB[16][17];
  __shared__ float mv[16][2];
  __shared__ float u6p[16][6][2];
  int tid = threadIdx.x;
  int i0 = blockIdx.x*16;
  int wave = tid>>6, lane = tid&63, quad = lane>>4, l16 = lane&15;
  int r = tid>>4, c0 = (tid&15)*16;
  float v[16];
  // phase A: ipa = cat @ Wo + bo  -> Bs
  {
    floatx4 acc[4] = {};
    const float* arow = cat + (size_t)(i0 + l16)*CATd + quad*8;
    const __hip_bfloat16* bbase = Wo + (size_t)(wave*4)*1024 + (size_t)lane*8;
    for (int k0=0; k0<CATd; k0+=32){
      float4 v0 = *(const float4*)(arow + k0);
      float4 v1 = *(const float4*)(arow + k0 + 4);
      float av[8] = {v0.x,v0.y,v0.z,v0.w,v1.x,v1.y,v1.z,v1.w};
      shortx8 ahi, alo;
      #pragma unroll
      for (int j=0; j<8; j++){
        short hh = f2bf(av[j]);
        ahi[j] = hh; alo[j] = f2bf(av[j] - bf2f(hh));
      }
      const __hip_bfloat16* bt = bbase + (size_t)(k0>>5)*16*1024;
      #pragma unroll
      for (int s=0; s<4; s++){
        shortx8 bhi = *(const shortx8*)(bt + s*1024);
        shortx8 blo = *(const shortx8*)(bt + s*1024 + 512);
        acc[s] = __builtin_amdgcn_mfma_f32_16x16x32_bf16(ahi, bhi, acc[s], 0, 0, 0);
        acc[s] = __builtin_amdgcn_mfma_f32_16x16x32_bf16(alo, bhi, acc[s], 0, 0, 0);
        acc[s] = __builtin_amdgcn_mfma_f32_16x16x32_bf16(ahi, blo, acc[s], 0, 0, 0);
      }
    }
    #pragma unroll
    for (int s=0; s<4; s++){
      int n = wave*64 + s*16 + l16;
      float bs = bo[n];
      #pragma unroll
      for (int rr=0; rr<4; rr++) Bs[quad*4+rr][n] = acc[s][rr] + bs;
    }
  }
  __syncthreads();
  // stage 0: LN(sc + ipa)
  {
    const float* sr = scb + (size_t)(i0+r)*CSd + c0;
    float s1=0.f, s2=0.f;
    #pragma unroll
    for (int k2=0;k2<16;k2++){ float x = sr[k2] + Bs[r][c0+k2]; v[k2]=x; s1+=x; s2+=x*x; }
    rA[r][tid&15]=s1; rB[r][tid&15]=s2;
  }
  __syncthreads();
  if (tid<16){
    float s1=0.f,s2=0.f;
    #pragma unroll
    for (int c=0;c<16;c++){ s1+=rA[tid][c]; s2+=rB[tid][c]; }
    float mu = s1*(1.f/CSd), var = s2*(1.f/CSd) - mu*mu;
    mv[tid][0]=mu; mv[tid][1]=rsqrtf(var+1e-5f);
  }
  __syncthreads();
  {
    float mu=mv[r][0], rs=mv[r][1];
    #pragma unroll
    for (int k2=0;k2<16;k2++) As[r][c0+k2] = (v[k2]-mu)*rs*gi_[c0+k2] + bi_[c0+k2];
  }
  __syncthreads();
  gemm_stage(As, Bs, W1, c1, true, tid);
  __syncthreads();
  gemm_stage(Bs, Cs, W2, c2, true, tid);
  __syncthreads();
  gemm_stage(Cs, Bs, W3, c3, false, tid);
  __syncthreads();
  // stage 4: LN(sc_new + tr3*mask)
  {
    float mk = mask[i0+r];
    float s1=0.f, s2=0.f;
    #pragma unroll
    for (int k2=0;k2<16;k2++){ float x = As[r][c0+k2] + Bs[r][c0+k2]*mk; v[k2]=x; s1+=x; s2+=x*x; }
    rA[r][tid&15]=s1; rB[r][tid&15]=s2;
  }
  __syncthreads();
  if (tid<16){
    float s1=0.f,s2=0.f;
    #pragma unroll
    for (int c=0;c<16;c++){ s1+=rA[tid][c]; s2+=rB[tid][c]; }
    float mu = s1*(1.f/CSd), var = s2*(1.f/CSd) - mu*mu;
    mv[tid][0]=mu; mv[tid][1]=rsqrtf(var+1e-5f);
  }
  __syncthreads();
  {
    float mu=mv[r][0], rs=mv[r][1];
    float* out = scb + (size_t)(i0+r)*CSd + c0;
    #pragma unroll
    for (int k2=0;k2<16;k2++){
      float o = (v[k2]-mu)*rs*gt_[c0+k2] + bt_[c0+k2];
      As[r][c0+k2] = o;
      out[k2] = o;
    }
  }
  __syncthreads();
  // stage 5: upd (192-thread k-split) + quat update
  if (tid < 192){
    int rr = tid/12, o = (tid%12)>>1, half = tid&1;
    float acc = half ? 0.f : bbb[o];
    int kb = half*128;
    for (int k2=kb; k2<kb+128; k2++) acc += As[rr][k2]*wbb[k2*6+o];
    u6p[rr][o][half] = acc;
  }
  __syncthreads();
  if (tid < 16){
    int gidx = i0 + tid;
    float uu[6];
    #pragma unroll
    for (int o=0;o<6;o++) uu[o] = u6p[tid][o][0] + u6p[tid][o][1];
    float bq = uu[0], cq = uu[1], dq = uu[2];
    float norm = sqrtf(1.f + bq*bq + cq*cq + dq*dq);
    float a = 1.f/norm, b_ = bq/norm, c_ = cq/norm, d_ = dq/norm;
    float dR[9];
    dR[0] = a*a + b_*b_ - c_*c_ - d_*d_; dR[1] = 2.f*(b_*c_ - a*d_); dR[2] = 2.f*(b_*d_ + a*c_);
    dR[3] = 2.f*(b_*c_ + a*d_); dR[4] = a*a - b_*b_ + c_*c_ - d_*d_; dR[5] = 2.f*(c_*d_ - a*b_);
    dR[6] = 2.f*(b_*d_ - a*c_); dR[7] = 2.f*(c_*d_ + a*b_); dR[8] = a*a - b_*b_ - c_*c_ + d_*d_;
    float mk = mask[gidx];
    float dt0 = uu[3]*mk, dt1 = uu[4]*mk, dt2 = uu[5]*mk;
    float Rm[9];
    #pragma unroll
    for (int ii=0; ii<9; ii++) Rm[ii] = R[gidx*9+ii];
    t[gidx*3]   += Rm[0]*dt0 + Rm[1]*dt1 + Rm[2]*dt2;
    t[gidx*3+1] += Rm[3]*dt0 + Rm[4]*dt1 + Rm[5]*dt2;
    t[gidx*3+2] += Rm[6]*dt0 + Rm[7]*dt1 + Rm[8]*dt2;
    #pragma unroll
    for (int ii=0; ii<3; ii++)
      #pragma unroll
      for (int jj=0; jj<3; jj++)
        R[gidx*9 + ii*3 + jj] = Rm[ii*3]*dR[jj] + Rm[ii*3+1]*dR[3+jj] + Rm[ii*3+2]*dR[6+jj];
  }
}

// ------------- final output write -------------
__global__ __launch_bounds__(256) void k_writeout(
    const float* __restrict__ sc, const float* __restrict__ R, const float* __restrict__ t,
    float* __restrict__ out){
  int idx = blockIdx.x*256 + threadIdx.x;
  if      (idx < 131072) out[idx] = sc[idx];
  else if (idx < 135680) out[idx] = R[idx-131072];
  else if (idx < 137216) out[idx] = t[idx-135680];
}

extern "C" void kernel_launch(void* const* d_in, const int* in_sizes, int n_in,
                              void* d_out, int out_size, void* d_ws, size_t ws_size,
                              hipStream_t stream){
  const float* s      = (const float*)d_in[0];
  const float* z      = (const float*)d_in[1];
  const float* mask   = (const float*)d_in[2];
  const float* ln_s_g = (const float*)d_in[3];
  const float* ln_s_b = (const float*)d_in[4];
  const float* ln_z_g = (const float*)d_in[5];
  const float* ln_z_b = (const float*)d_in[6];
  const float* w_init = (const float*)d_in[7];
  const float* b_init = (const float*)d_in[8];
  const float* ln_ipa_g = (const float*)d_in[9];
  const float* ln_ipa_b = (const float*)d_in[10];
  const float* ln_tr_g  = (const float*)d_in[11];
  const float* ln_tr_b  = (const float*)d_in[12];
  const float* wq = (const float*)d_in[13]; const float* bq = (const float*)d_in[14];
  const float* wk = (const float*)d_in[15]; const float* bk = (const float*)d_in[16];
  const float* wv = (const float*)d_in[17]; const float* bv = (const float*)d_in[18];
  const float* wqp = (const float*)d_in[19]; const float* bqp = (const float*)d_in[20];
  const float* wkp = (const float*)d_in[21]; const float* bkp = (const float*)d_in[22];
  const float* wvp = (const float*)d_in[23]; const float* bvp = (const float*)d_in[24];
  const float* wpb = (const float*)d_in[25];
  const float* head_w = (const float*)d_in[26];
  const float* wo = (const float*)d_in[27]; const float* bo = (const float*)d_in[28];
  const float* wt1 = (const float*)d_in[29]; const float* bt1 = (const float*)d_in[30];
  const float* wt2 = (const float*)d_in[31]; const float* bt2 = (const float*)d_in[32];
  const float* wt3 = (const float*)d_in[33]; const float* bt3 = (const float*)d_in[34];
  const float* wbb = (const float*)d_in[35]; const float* bbb = (const float*)d_in[36];

  float* W = (float*)d_ws;
  float* scb   = W + OFF_SC;
  __half*  pbb  = (__half*)(W + OFF_PB);
  float* Pb    = W + OFF_P;
  float* qnb   = W + OFF_QN;
  float* knb   = W + OFF_KN;
  __hip_bfloat16* a16hi = (__hip_bfloat16*)(W + OFF_A16);
  __hip_bfloat16* a16lo = a16hi + 2097152;
  float* catb  = W + OFF_CAT;
  float* s0b   = W + OFF_S0;
  float* Rb    = W + OFF_R;
  float* tb    = W + OFF_T;
  float* gammab= W + OFF_GAMMA;
  float* maskb = W + OFF_MASKB;
  float* bcat  = W + OFF_BCAT;
  __hip_bfloat16* WinitP = (__hip_bfloat16*)(W + OFF_WINITP);
  __hip_bfloat16* Wt1P   = (__hip_bfloat16*)(W + OFF_WT1P);
  __hip_bfloat16* Wt2P   = (__hip_bfloat16*)(W + OFF_WT2P);
  __hip_bfloat16* Wt3P   = (__hip_bfloat16*)(W + OFF_WT3P);
  __hip_bfloat16* WoP    = (__hip_bfloat16*)(W + OFF_WOP);
  __hip_bfloat16* WcatP  = (__hip_bfloat16*)(W + OFF_WCATP);
  float* Qp = W + OFF_QP;
  __hip_bfloat16* Kp = (__hip_bfloat16*)(W + OFF_KP);
  __hip_bfloat16* Vp = (__hip_bfloat16*)(W + OFF_VP);
  __hip_bfloat16* znt = (__hip_bfloat16*)(W + OFF_ZNT);

  k_setup<<<9, 256, 0, stream>>>(bq,bk,bv,bqp,bkp,bvp, head_w, mask, bcat, gammab, maskb, Rb, tb);
  k_pack_cat<<<CSd*NPROJ/256, 256, 0, stream>>>(wq,wk,wv,wqp,wkp,wvp, WcatP);
  k_pack<<<256,  256, 0, stream>>>(w_init, CSd, CSd, WinitP);
  k_pack<<<1536, 256, 0, stream>>>(wo, CATd, CSd, WoP);
  k_pack<<<256,  256, 0, stream>>>(wt1, CSd, CSd, Wt1P);
  k_pack<<<256,  256, 0, stream>>>(wt2, CSd, CSd, Wt2P);
  k_pack<<<256,  256, 0, stream>>>(wt3, CSd, CSd, Wt3P);

  k_addln<<<Lq, 256, 0, stream>>>(s, nullptr, ln_s_g, ln_s_b, s0b);
  k_gemm_mfma<<<dim3(4,8), 256, 0, stream>>>(s0b, CSd, WinitP, CSd, b_init, scb, 0, nullptr);
  k_lnz_pb<<<Lq*Lq/64, 256, 0, stream>>>(z, ln_z_g, ln_z_b, wpb, pbb, znt);

  for (int it=0; it<8; ++it){
    k_gemm_mfma<<<dim3(18,8), 256, 0, stream>>>(scb, CSd, WcatP, NPROJ, bcat, Pb, 0, nullptr);
    k_packqkv<<<3072, 256, 0, stream>>>(Pb, Rb, tb, gammab, Qp, Kp, Vp, qnb, knb);
    k_attn<<<dim3(32,8), 256, 0, stream>>>(Qp, Kp, Vp, qnb, knb, pbb, maskb, gammab, Rb, tb,
                                           a16hi, a16lo, catb);
    k_opair_mfma<<<Lq, 256, 0, stream>>>(a16hi, a16lo, znt, catb);
    k_mega<<<32, 256, 0, stream>>>(scb, catb, WoP, bo, ln_ipa_g, ln_ipa_b,
                                   Wt1P, bt1, Wt2P, bt2, Wt3P, bt3,
                                   ln_tr_g, ln_tr_b, mask, wbb, bbb, Rb, tb);
  }
  k_writeout<<<536, 256, 0, stream>>>(scb, Rb, tb, (float*)d_out);
}

// Round 9
// 1231.268 us; speedup vs baseline: 1.3531x; 1.0486x over previous
//
#include <hip/hip_runtime.h>
#include <hip/hip_bf16.h>
#include <hip/hip_fp16.h>
#include <math.h>

#define Lq 512
#define CSd 256
#define CZd 128
#define Hd 8
#define CHd 32
#define PQd 4
#define PVd 8
#define CATd 1536
#define NPROJ 1152

typedef __attribute__((ext_vector_type(4))) float floatx4;
typedef __attribute__((ext_vector_type(8))) short shortx8;

// ---------------- ws layout (float offsets) ----------------
#define OFF_SC      0         // 131072
#define OFF_PB      393216    // 1048576 (half)
#define OFF_P       1441792   // 589824
#define OFF_QN      2031616   // 4096
#define OFF_KN      2035712   // 4096
#define OFF_A16     2039808   // 2097152 (a16hi only; lo region unused now)
#define OFF_CAT     4136960   // 786432
#define OFF_S0      4923392   // 131072
#define OFF_R       5054464   // 4608
#define OFF_T       5059072   // 1536
#define OFF_GAMMA   5060608   // 8
#define OFF_MASKB   5060616   // 512
#define OFF_BCAT    5061128   // 1152
#define OFF_WINITP  5062280   // 65536
#define OFF_WT1P    5127816   // 65536
#define OFF_WT2P    5193352   // 65536
#define OFF_WT3P    5258888   // 65536
#define OFF_WOP     5324424   // 393216
#define OFF_WCATP   5717640   // 294912
#define OFF_QP      6012552   // 262144 (fp32)
#define OFF_KP      6274696   // 262144 (=524288 bf16)
#define OFF_VP      6536840   // 262144 (=524288 bf16)
#define OFF_ZNT     6798984   // 16777216 (=33554432 bf16)  [i][c][j]

#define WLC 0.57735026918962576f
#define WCC 0.23570226039551584f
#define ISC 0.17677669529663687f

__device__ __forceinline__ float wave_sum(float v){
  #pragma unroll
  for (int m=32; m; m>>=1) v += __shfl_xor(v, m);
  return v;
}
__device__ __forceinline__ short f2bf(float v){
  __hip_bfloat16 h = (__hip_bfloat16)v;
  return __builtin_bit_cast(short, h);
}
__device__ __forceinline__ float bf2f(short s){
  unsigned u = ((unsigned)(unsigned short)s) << 16;
  return __builtin_bit_cast(float, u);
}
__device__ __forceinline__ __hip_bfloat16 s2b(short s){
  return __builtin_bit_cast(__hip_bfloat16, s);
}

// ------------- setup -------------
__global__ __launch_bounds__(256) void k_setup(
    const float* __restrict__ bq, const float* __restrict__ bk, const float* __restrict__ bv,
    const float* __restrict__ bqp, const float* __restrict__ bkp, const float* __restrict__ bvp,
    const float* __restrict__ head_w, const float* __restrict__ mask,
    float* __restrict__ bcat, float* __restrict__ gamma,
    float* __restrict__ maskb, float* __restrict__ R, float* __restrict__ t){
  int k = blockIdx.x*256 + threadIdx.x;
  if (k < NPROJ){
    float v;
    if      (k < 256) v = bq[k];
    else if (k < 512) v = bk[k-256];
    else if (k < 768) v = bv[k-512];
    else if (k < 864) v = bqp[k-768];
    else if (k < 960) v = bkp[k-864];
    else              v = bvp[k-960];
    bcat[k] = v;
    return;
  }
  k -= NPROJ;
  if (k < Hd){ gamma[k] = log1pf(expf(head_w[k])); return; }
  k -= Hd;
  if (k < Lq){ maskb[k] = (mask[k] - 1.f)*1e9f; return; }
  k -= Lq;
  if (k < Lq){
    #pragma unroll
    for (int ii=0; ii<9; ii++) R[k*9+ii] = (ii==0||ii==4||ii==8) ? 1.f : 0.f;
    t[k*3] = 0.f; t[k*3+1] = 0.f; t[k*3+2] = 0.f;
  }
}

// ------------- pack [K,N] fp32 weight into MFMA-B hi/lo bf16 layout -------------
__global__ __launch_bounds__(256) void k_pack(
    const float* __restrict__ W, int K, int N, __hip_bfloat16* __restrict__ out){
  int idx = blockIdx.x*256 + threadIdx.x;
  if (idx >= K*N) return;
  int j = idx & 7, lane = (idx>>3) & 63, rest = idx >> 9;
  int nt = N >> 4;
  int tn = rest % nt, tk = rest / nt;
  int k = tk*32 + (lane>>4)*8 + j;
  int n = tn*16 + (lane&15);
  float v = W[(size_t)k*N + n];
  short h = f2bf(v);
  short l = f2bf(v - bf2f(h));
  size_t base = (size_t)rest*1024 + (idx & 511);
  out[base]       = s2b(h);
  out[base + 512] = s2b(l);
}

// ------------- pack concatenated projection weight (virtual [256,1152]) -------------
__global__ __launch_bounds__(256) void k_pack_cat(
    const float* __restrict__ wq, const float* __restrict__ wk, const float* __restrict__ wv,
    const float* __restrict__ wqp, const float* __restrict__ wkp, const float* __restrict__ wvp,
    __hip_bfloat16* __restrict__ out){
  int idx = blockIdx.x*256 + threadIdx.x;
  if (idx >= CSd*NPROJ) return;
  int j = idx & 7, lane = (idx>>3) & 63, rest = idx >> 9;
  const int nt = NPROJ >> 4;
  int tn = rest % nt, tk = rest / nt;
  int k = tk*32 + (lane>>4)*8 + j;
  int n = tn*16 + (lane&15);
  float v;
  if      (n < 256) v = wq[k*256 + n];
  else if (n < 512) v = wk[k*256 + n-256];
  else if (n < 768) v = wv[k*256 + n-512];
  else if (n < 864) v = wqp[k*96 + n-768];
  else if (n < 960) v = wkp[k*96 + n-864];
  else              v = wvp[k*192 + n-960];
  short h = f2bf(v);
  short l = f2bf(v - bf2f(h));
  size_t base = (size_t)rest*1024 + (idx & 511);
  out[base]       = s2b(h);
  out[base + 512] = s2b(l);
}

// ------------- split-precision MFMA GEMM; NST = 16-col tiles per block -------------
template<int NST>
__global__ __launch_bounds__(256) void k_gemm_mfma(
    const float* __restrict__ A, int K,
    const __hip_bfloat16* __restrict__ Bp, int N,
    const float* __restrict__ bias,
    float* __restrict__ Cf,
    int relu, const float* __restrict__ rowscale){
  int tid = threadIdx.x;
  int wave = tid>>6, lane = tid&63;
  int i0 = blockIdx.y*64 + wave*16;
  int n0 = blockIdx.x*(NST*16);
  int quad = lane>>4, l16 = lane&15;
  floatx4 acc[NST] = {};
  const int ntiles = N >> 4;
  const float* arow = A + (size_t)(i0 + l16)*K + quad*8;
  const __hip_bfloat16* bbase = Bp + ((size_t)(n0>>4))*1024 + (size_t)(lane&63)*8;
  for (int k0=0; k0<K; k0+=32){
    float4 v0 = *(const float4*)(arow + k0);
    float4 v1 = *(const float4*)(arow + k0 + 4);
    float av[8] = {v0.x,v0.y,v0.z,v0.w,v1.x,v1.y,v1.z,v1.w};
    shortx8 ahi, alo;
    #pragma unroll
    for (int j=0; j<8; j++){
      short h = f2bf(av[j]);
      ahi[j] = h;
      alo[j] = f2bf(av[j] - bf2f(h));
    }
    const __hip_bfloat16* bt = bbase + (size_t)(k0>>5)*ntiles*1024;
    #pragma unroll
    for (int s=0; s<NST; s++){
      shortx8 bhi = *(const shortx8*)(bt + s*1024);
      shortx8 blo = *(const shortx8*)(bt + s*1024 + 512);
      acc[s] = __builtin_amdgcn_mfma_f32_16x16x32_bf16(ahi, bhi, acc[s], 0, 0, 0);
      acc[s] = __builtin_amdgcn_mfma_f32_16x16x32_bf16(alo, bhi, acc[s], 0, 0, 0);
      acc[s] = __builtin_amdgcn_mfma_f32_16x16x32_bf16(ahi, blo, acc[s], 0, 0, 0);
    }
  }
  #pragma unroll
  for (int s=0; s<NST; s++){
    int n = n0 + s*16 + l16;
    float bs = bias ? bias[n] : 0.f;
    #pragma unroll
    for (int r=0; r<4; r++){
      int m = i0 + quad*4 + r;
      float v = acc[s][r] + bs;
      if (relu) v = fmaxf(v, 0.f);
      if (rowscale) v *= rowscale[m];
      Cf[(size_t)m*N + n] = v;
    }
  }
}

// ------------- LN over CS=256 row -------------
__global__ __launch_bounds__(256) void k_addln(
    const float* __restrict__ x, const float* __restrict__ y,
    const float* __restrict__ g, const float* __restrict__ b,
    float* __restrict__ out){
  __shared__ float red[4];
  int row = blockIdx.x, tid = threadIdx.x;
  float v = x[row*CSd + tid];
  if (y) v += y[row*CSd + tid];
  int wid = tid>>6, lane = tid&63;
  float s = wave_sum(v);
  if (lane==0) red[wid] = s;
  __syncthreads();
  float mu = (red[0]+red[1]+red[2]+red[3]) * (1.f/CSd);
  __syncthreads();
  float d = v - mu;
  float s2 = wave_sum(d*d);
  if (lane==0) red[wid] = s2;
  __syncthreads();
  float var = (red[0]+red[1]+red[2]+red[3]) * (1.f/CSd);
  float rs = rsqrtf(var + 1e-5f);
  out[row*CSd + tid] = d*rs*g[tid] + b[tid];
}

// ------------- zn LN: pair_bias (half) + znt bf16 [i][c][j] -------------
__global__ __launch_bounds__(256) void k_lnz_pb(
    const float* __restrict__ z, const float* __restrict__ g, const float* __restrict__ b,
    const float* __restrict__ wpb, __half* __restrict__ pb, __hip_bfloat16* __restrict__ znt){
  __shared__ float Zt[64*129];
  __shared__ float gwt[8][132];
  __shared__ float AB[16];
  __shared__ float red[64*4*11];
  __shared__ float mvl[64][2];
  int tid = threadIdx.x;
  size_t row0 = (size_t)blockIdx.x*64;
  int ib = (int)(row0 >> 9), j0 = (int)(row0 & 511);
  const float4* zsrc = (const float4*)(z + row0*CZd);
  #pragma unroll
  for (int it=0; it<8; it++){
    int idx = tid + it*256;
    int rr = idx>>5, qq = idx&31;
    float4 v = zsrc[idx];
    float* dst = &Zt[rr*129 + qq*4];
    dst[0]=v.x; dst[1]=v.y; dst[2]=v.z; dst[3]=v.w;
  }
  for (int idx=tid; idx<1024; idx+=256){
    int h = idx&7, c = idx>>3;
    gwt[h][c] = g[c]*wpb[c*8+h];
  }
  if (tid < 16){
    int h = tid&7; const float* src = (tid<8) ? g : b;
    float s = 0.f;
    for (int c=0; c<128; c++) s += src[c]*wpb[c*8+h];
    AB[tid] = s;
  }
  __syncthreads();
  int q = tid>>6, r = tid&63;
  const float* zr = &Zt[r*129 + q*32];
  float zv[32];
  #pragma unroll
  for (int t=0; t<32; t++) zv[t] = zr[t];
  float S1=0.f, S2=0.f;
  #pragma unroll
  for (int t=0; t<32; t++){ S1 += zv[t]; S2 += zv[t]*zv[t]; }
  float* rd = &red[(r*4+q)*11];
  rd[8]=S1; rd[9]=S2;
  #pragma unroll
  for (int h=0; h<8; h++){
    const float4* gw4 = (const float4*)&gwt[h][q*32];
    float d = 0.f;
    #pragma unroll
    for (int t4=0; t4<8; t4++){
      float4 gv = gw4[t4];
      d += zv[t4*4]*gv.x + zv[t4*4+1]*gv.y + zv[t4*4+2]*gv.z + zv[t4*4+3]*gv.w;
    }
    rd[h] = d;
  }
  __syncthreads();
  if (tid < 64){
    int rr = tid;
    const float* r0 = &red[rr*44];
    float acc[10];
    #pragma unroll
    for (int v=0; v<10; v++) acc[v] = r0[v] + r0[11+v] + r0[22+v] + r0[33+v];
    float mu  = acc[8]*(1.f/128.f);
    float var = acc[9]*(1.f/128.f) - mu*mu;
    float rs  = rsqrtf(var + 1e-5f);
    mvl[rr][0] = mu; mvl[rr][1] = rs;
    int j = j0 + rr;
    #pragma unroll
    for (int h=0; h<8; h++){
      float pbv = rs*(acc[h] - mu*AB[h]) + AB[8+h];
      pb[((size_t)(h*Lq+ib))*Lq + j] = __float2half(pbv);
    }
  }
  __syncthreads();
  #pragma unroll
  for (int it2=0; it2<32; it2++){
    int idx = it2*256 + tid;
    int c = idx >> 6, jo = idx & 63;
    float mu = mvl[jo][0], rs = mvl[jo][1];
    float zn = (Zt[jo*129 + c] - mu)*rs*g[c] + b[c];
    znt[((size_t)ib*128 + c)*512 + j0 + jo] = (__hip_bfloat16)zn;
  }
}

// ------------- pack Q'/K'/V' in MFMA layouts, compute qn/kn -------------
__global__ __launch_bounds__(256) void k_packqkv(
    const float* __restrict__ P, const float* __restrict__ R, const float* __restrict__ t,
    const float* __restrict__ gamma,
    float* __restrict__ Qp, __hip_bfloat16* __restrict__ Kp, __hip_bfloat16* __restrict__ Vp,
    float* __restrict__ qn, float* __restrict__ kn){
  int idx = blockIdx.x*256 + threadIdx.x;   // 3*262144
  int region = idx >> 18;
  int rem = idx & 262143;
  int h = rem >> 15;
  int r2 = rem & 32767;
  if (region == 0){
    int j = r2 >> 6, f = r2 & 63;
    float val = 0.f;
    if (f < 32) val = P[(size_t)j*NPROJ + 256 + h*CHd + f];
    else if (f < 44){
      int p = (f-32)/3, ax = (f-32)%3;
      const float* kp = P + (size_t)j*NPROJ + 864 + h*12 + p*3;
      const float* Rr = R + j*9 + ax*3;
      val = Rr[0]*kp[0] + Rr[1]*kp[1] + Rr[2]*kp[2] + t[j*3+ax];
    }
    short hi = f2bf(val), lo = f2bf(val - bf2f(hi));
    int kc = f>>5, jt = j>>4, l16 = j&15, fl = f&31, quad = fl>>3, jj = f&7;
    size_t base = (size_t)((h*2+kc)*32 + jt)*1024 + (quad*16+l16)*8 + jj;
    Kp[base] = s2b(hi);
    Kp[base+512] = s2b(lo);
    if (f == 0){
      const float* Rm = R + j*9; const float* tv = t + j*3;
      float acc = 0.f;
      #pragma unroll
      for (int p=0; p<PQd; p++){
        const float* kp = P + (size_t)j*NPROJ + 864 + h*12 + p*3;
        #pragma unroll
        for (int ax=0; ax<3; ax++){
          float g = Rm[ax*3]*kp[0] + Rm[ax*3+1]*kp[1] + Rm[ax*3+2]*kp[2] + tv[ax];
          acc += g*g;
        }
      }
      kn[j*Hd + h] = acc;
    }
  } else if (region == 1){
    int j = r2 >> 6, n = r2 & 63;
    float val = 0.f;
    if (n < 32) val = P[(size_t)j*NPROJ + 512 + h*CHd + n];
    else if (n < 56){
      int p = (n-32)/3, ax = (n-32)%3;
      const float* vp = P + (size_t)j*NPROJ + 960 + h*24 + p*3;
      const float* Rr = R + j*9 + ax*3;
      val = Rr[0]*vp[0] + Rr[1]*vp[1] + Rr[2]*vp[2] + t[j*3+ax];
    }
    short hi = f2bf(val), lo = f2bf(val - bf2f(hi));
    int kc2 = j>>5, w = n>>4, l16 = n&15, jl = j&31, quad = jl>>3, jj = j&7;
    size_t base = (size_t)((h*16+kc2)*4 + w)*1024 + (quad*16+l16)*8 + jj;
    Vp[base] = s2b(hi);
    Vp[base+512] = s2b(lo);
  } else {
    int i = r2 >> 6, f = r2 & 63;
    float val = 0.f;
    if (f < 32) val = P[(size_t)i*NPROJ + h*CHd + f] * (WLC*ISC);
    else if (f < 44){
      int p = (f-32)/3, ax = (f-32)%3;
      const float* qp = P + (size_t)i*NPROJ + 768 + h*12 + p*3;
      const float* Rr = R + i*9 + ax*3;
      float g = Rr[0]*qp[0] + Rr[1]*qp[1] + Rr[2]*qp[2] + t[i*3+ax];
      val = g * (WLC*WCC*gamma[h]);
    }
    Qp[((size_t)h*512 + i)*64 + f] = val;
    if (f == 0){
      const float* Rm = R + i*9; const float* tv = t + i*3;
      float acc = 0.f;
      #pragma unroll
      for (int p=0; p<PQd; p++){
        const float* qp = P + (size_t)i*NPROJ + 768 + h*12 + p*3;
        #pragma unroll
        for (int ax=0; ax<3; ax++){
          float g = Rm[ax*3]*qp[0] + Rm[ax*3+1]*qp[1] + Rm[ax*3+2]*qp[2] + tv[ax];
          acc += g*g;
        }
      }
      qn[i*Hd + h] = acc;
    }
  }
}

// ------------- fused attention (a16 hi-only) -------------
__global__ __launch_bounds__(256) void k_attn(
    const float* __restrict__ Qp, const __hip_bfloat16* __restrict__ Kp,
    const __hip_bfloat16* __restrict__ Vp,
    const float* __restrict__ qn, const float* __restrict__ kn,
    const __half* __restrict__ pb, const float* __restrict__ maskb,
    const float* __restrict__ gamma,
    const float* __restrict__ R, const float* __restrict__ t,
    __hip_bfloat16* __restrict__ a16hi,
    float* __restrict__ cat){
  __shared__ float At[16][516];
  __shared__ float Ot[16][36];
  __shared__ float red1[16][16];
  __shared__ float red2[16][16];
  __shared__ float invL[16];
  __shared__ float qnL[16];
  int tid = threadIdx.x;
  int i0 = blockIdx.x*16, h = blockIdx.y;
  int wave = tid>>6, lane = tid&63, quad = lane>>4, l16 = lane&15;
  float gam = gamma[h];
  float coef = 0.5f*WLC*WCC*gam;
  if (tid < 16) qnL[tid] = qn[(i0+tid)*Hd + h];
  __syncthreads();
  const float* qrow = Qp + ((size_t)h*512 + i0 + l16)*64 + quad*8;
  shortx8 qhi[2], qlo[2];
  #pragma unroll
  for (int kc=0; kc<2; kc++){
    float4 v0 = *(const float4*)(qrow + kc*32);
    float4 v1 = *(const float4*)(qrow + kc*32 + 4);
    float av[8] = {v0.x,v0.y,v0.z,v0.w,v1.x,v1.y,v1.z,v1.w};
    #pragma unroll
    for (int j=0; j<8; j++){
      short hh = f2bf(av[j]);
      qhi[kc][j] = hh; qlo[kc][j] = f2bf(av[j] - bf2f(hh));
    }
  }
  for (int it=0; it<8; it++){
    int jt = it*4 + wave;
    floatx4 acc = {};
    #pragma unroll
    for (int kc=0; kc<2; kc++){
      const __hip_bfloat16* bt = Kp + (size_t)((h*2+kc)*32 + jt)*1024 + lane*8;
      shortx8 bhi = *(const shortx8*)bt;
      shortx8 blo = *(const shortx8*)(bt + 512);
      acc = __builtin_amdgcn_mfma_f32_16x16x32_bf16(qhi[kc], bhi, acc, 0, 0, 0);
      acc = __builtin_amdgcn_mfma_f32_16x16x32_bf16(qlo[kc], bhi, acc, 0, 0, 0);
      acc = __builtin_amdgcn_mfma_f32_16x16x32_bf16(qhi[kc], blo, acc, 0, 0, 0);
    }
    int j = jt*16 + l16;
    float knj = kn[j*Hd + h];
    float mbj = maskb[j];
    #pragma unroll
    for (int r=0; r<4; r++){
      int i = quad*4 + r;
      float pbv = __half2float(pb[((size_t)(h*Lq) + i0 + i)*Lq + j]);
      At[i][j] = acc[r] + WLC*pbv + mbj - coef*(qnL[i] + knj);
    }
  }
  __syncthreads();
  int srow = tid>>4, sseg = tid&15;
  {
    float m = -1e30f;
    #pragma unroll 8
    for (int k2=0; k2<32; k2++) m = fmaxf(m, At[srow][sseg + k2*16]);
    red1[srow][sseg] = m;
  }
  __syncthreads();
  float mrow = red1[srow][0];
  #pragma unroll
  for (int c=1;c<16;c++) mrow = fmaxf(mrow, red1[srow][c]);
  {
    float ssum = 0.f;
    #pragma unroll 8
    for (int k2=0; k2<32; k2++){
      int cc = sseg + k2*16;
      float e = __expf(At[srow][cc]-mrow);
      At[srow][cc] = e; ssum += e;
    }
    red2[srow][sseg] = ssum;
  }
  __syncthreads();
  if (tid < 16){
    float s=0.f;
    #pragma unroll
    for (int c=0;c<16;c++) s += red2[tid][c];
    invL[tid] = 1.f/s;
  }
  __syncthreads();
  for (int idx2=tid; idx2<8192; idx2+=256){
    int rr = idx2>>9, cc = idx2&511;
    float v = At[rr][cc]*invL[rr];
    At[rr][cc] = v;
    size_t ai = (((size_t)(i0+rr)*16 + (cc>>5))*8 + h)*32 + (cc&31);
    a16hi[ai] = s2b(f2bf(v));
  }
  __syncthreads();
  floatx4 acc2 = {};
  for (int kc2=0; kc2<16; kc2++){
    const float* ar = &At[l16][kc2*32 + quad*8];
    float4 v0 = *(const float4*)ar;
    float4 v1 = *(const float4*)(ar+4);
    float av[8] = {v0.x,v0.y,v0.z,v0.w,v1.x,v1.y,v1.z,v1.w};
    shortx8 ahi, alo;
    #pragma unroll
    for (int j=0; j<8; j++){
      short hh = f2bf(av[j]);
      ahi[j] = hh; alo[j] = f2bf(av[j] - bf2f(hh));
    }
    const __hip_bfloat16* bt = Vp + (size_t)((h*16+kc2)*4 + wave)*1024 + lane*8;
    shortx8 bhi = *(const shortx8*)bt;
    shortx8 blo = *(const shortx8*)(bt + 512);
    acc2 = __builtin_amdgcn_mfma_f32_16x16x32_bf16(ahi, bhi, acc2, 0, 0, 0);
    acc2 = __builtin_amdgcn_mfma_f32_16x16x32_bf16(alo, bhi, acc2, 0, 0, 0);
    acc2 = __builtin_amdgcn_mfma_f32_16x16x32_bf16(ahi, blo, acc2, 0, 0, 0);
  }
  {
    int n = wave*16 + l16;
    #pragma unroll
    for (int r=0;r<4;r++){
      int i = quad*4+r;
      if (n < 32) cat[(size_t)(i0+i)*CATd + h*CHd + n] = acc2[r];
      else        Ot[i][n-32] = acc2[r];
    }
  }
  __syncthreads();
  if (tid < 128){
    int i = tid>>3, p = tid&7, gi = i0+i;
    float o0 = Ot[i][p*3], o1 = Ot[i][p*3+1], o2 = Ot[i][p*3+2];
    float d0 = o0 - t[gi*3], d1 = o1 - t[gi*3+1], d2 = o2 - t[gi*3+2];
    const float* Rm = R + gi*9;
    float l0 = Rm[0]*d0 + Rm[3]*d1 + Rm[6]*d2;
    float l1 = Rm[1]*d0 + Rm[4]*d1 + Rm[7]*d2;
    float l2 = Rm[2]*d0 + Rm[5]*d1 + Rm[8]*d2;
    float* cr = cat + (size_t)gi*CATd;
    cr[256 + h*24 + p*3]   = l0;
    cr[256 + h*24 + p*3+1] = l1;
    cr[256 + h*24 + p*3+2] = l2;
    cr[448 + h*8 + p] = sqrtf(l0*l0 + l1*l1 + l2*l2 + 1e-8f);
  }
}

// ------------- opair = a @ zn via MFMA (a hi-only) -------------
__global__ __launch_bounds__(256) void k_opair_mfma(
    const __hip_bfloat16* __restrict__ a16hi,
    const __hip_bfloat16* __restrict__ znt, float* __restrict__ cat){
  int i = blockIdx.x;
  int tid = threadIdx.x;
  int wave = tid>>6, lane = tid&63, quad = lane>>4, l16 = lane&15;
  int nt0 = wave*2, nt1 = wave*2+1;
  floatx4 acc0 = {}, acc1 = {};
  const __hip_bfloat16* abase_h = a16hi + ((size_t)i*16*8 + (l16&7))*32 + quad*8;
  const __hip_bfloat16* zb0 = znt + ((size_t)i*128 + nt0*16 + l16)*512 + quad*8;
  const __hip_bfloat16* zb1 = znt + ((size_t)i*128 + nt1*16 + l16)*512 + quad*8;
  #pragma unroll
  for (int kt=0; kt<16; kt++){
    shortx8 ah = *(const shortx8*)(abase_h + kt*256);
    shortx8 b0 = *(const shortx8*)(zb0 + kt*32);
    shortx8 b1 = *(const shortx8*)(zb1 + kt*32);
    acc0 = __builtin_amdgcn_mfma_f32_16x16x32_bf16(ah, b0, acc0, 0, 0, 0);
    acc1 = __builtin_amdgcn_mfma_f32_16x16x32_bf16(ah, b1, acc1, 0, 0, 0);
  }
  if (quad < 2){
    float* cr = cat + (size_t)i*CATd + 512;
    #pragma unroll
    for (int r=0; r<4; r++){
      int h = quad*4 + r;
      cr[h*CZd + nt0*16 + l16] = acc0[r];
      cr[h*CZd + nt1*16 + l16] = acc1[r];
    }
  }
}

// ------------- mega: wo-GEMM + LN + 3 GEMMs + LN + upd + frame update -------------
__device__ __forceinline__ void gemm_stage(
    const float (*X)[260], float (*Y)[260],
    const __hip_bfloat16* __restrict__ Wp, const float* __restrict__ bias,
    bool relu, int tid){
  int wave = tid>>6, lane = tid&63, quad = lane>>4, l16 = lane&15;
  floatx4 acc[4] = {};
  for (int kc=0; kc<8; kc++){
    const float* xr = &X[l16][kc*32 + quad*8];
    float4 v0 = *(const float4*)xr;
    float4 v1 = *(const float4*)(xr+4);
    float av[8] = {v0.x,v0.y,v0.z,v0.w,v1.x,v1.y,v1.z,v1.w};
    shortx8 ahi, alo;
    #pragma unroll
    for (int j=0; j<8; j++){
      short hh = f2bf(av[j]);
      ahi[j] = hh; alo[j] = f2bf(av[j] - bf2f(hh));
    }
    #pragma unroll
    for (int ns=0; ns<4; ns++){
      const __hip_bfloat16* bt = Wp + (size_t)(kc*16 + wave*4 + ns)*1024 + lane*8;
      shortx8 bhi = *(const shortx8*)bt;
      shortx8 blo = *(const shortx8*)(bt + 512);
      acc[ns] = __builtin_amdgcn_mfma_f32_16x16x32_bf16(ahi, bhi, acc[ns], 0, 0, 0);
      acc[ns] = __builtin_amdgcn_mfma_f32_16x16x32_bf16(alo, bhi, acc[ns], 0, 0, 0);
      acc[ns] = __builtin_amdgcn_mfma_f32_16x16x32_bf16(ahi, blo, acc[ns], 0, 0, 0);
    }
  }
  #pragma unroll
  for (int ns=0; ns<4; ns++){
    int n = wave*64 + ns*16 + l16;
    float bs = bias[n];
    #pragma unroll
    for (int r=0;r<4;r++){
      float v = acc[ns][r] + bs;
      if (relu) v = fmaxf(v, 0.f);
      Y[quad*4+r][n] = v;
    }
  }
}

__global__ __launch_bounds__(256) void k_mega(
    float* __restrict__ scb, const float* __restrict__ cat,
    const __hip_bfloat16* __restrict__ Wo, const float* __restrict__ bo,
    const float* __restrict__ gi_, const float* __restrict__ bi_,
    const __hip_bfloat16* __restrict__ W1, const float* __restrict__ c1,
    const __hip_bfloat16* __restrict__ W2, const float* __restrict__ c2,
    const __hip_bfloat16* __restrict__ W3, const float* __restrict__ c3,
    const float* __restrict__ gt_, const float* __restrict__ bt_,
    const float* __restrict__ mask,
    const float* __restrict__ wbb, const float* __restrict__ bbb,
    float* __restrict__ R, float* __restrict__ t){
  __shared__ float As[16][260], Bs[16][260], Cs[16][260];
  __shared__ float rA[16][17], rB[16][17];
  __shared__ float mv[16][2];
  __shared__ float u6p[16][6][2];
  int tid = threadIdx.x;
  int i0 = blockIdx.x*16;
  int wave = tid>>6, lane = tid&63, quad = lane>>4, l16 = lane&15;
  int r = tid>>4, c0 = (tid&15)*16;
  float v[16];
  // phase A: ipa = cat @ Wo + bo  -> Bs
  {
    floatx4 acc[4] = {};
    const float* arow = cat + (size_t)(i0 + l16)*CATd + quad*8;
    const __hip_bfloat16* bbase = Wo + (size_t)(wave*4)*1024 + (size_t)lane*8;
    for (int k0=0; k0<CATd; k0+=32){
      float4 v0 = *(const float4*)(arow + k0);
      float4 v1 = *(const float4*)(arow + k0 + 4);
      float av[8] = {v0.x,v0.y,v0.z,v0.w,v1.x,v1.y,v1.z,v1.w};
      shortx8 ahi, alo;
      #pragma unroll
      for (int j=0; j<8; j++){
        short hh = f2bf(av[j]);
        ahi[j] = hh; alo[j] = f2bf(av[j] - bf2f(hh));
      }
      const __hip_bfloat16* bt = bbase + (size_t)(k0>>5)*16*1024;
      #pragma unroll
      for (int s=0; s<4; s++){
        shortx8 bhi = *(const shortx8*)(bt + s*1024);
        shortx8 blo = *(const shortx8*)(bt + s*1024 + 512);
        acc[s] = __builtin_amdgcn_mfma_f32_16x16x32_bf16(ahi, bhi, acc[s], 0, 0, 0);
        acc[s] = __builtin_amdgcn_mfma_f32_16x16x32_bf16(alo, bhi, acc[s], 0, 0, 0);
        acc[s] = __builtin_amdgcn_mfma_f32_16x16x32_bf16(ahi, blo, acc[s], 0, 0, 0);
      }
    }
    #pragma unroll
    for (int s=0; s<4; s++){
      int n = wave*64 + s*16 + l16;
      float bs = bo[n];
      #pragma unroll
      for (int rr=0; rr<4; rr++) Bs[quad*4+rr][n] = acc[s][rr] + bs;
    }
  }
  __syncthreads();
  // stage 0: LN(sc + ipa)
  {
    const float* sr = scb + (size_t)(i0+r)*CSd + c0;
    float s1=0.f, s2=0.f;
    #pragma unroll
    for (int k2=0;k2<16;k2++){ float x = sr[k2] + Bs[r][c0+k2]; v[k2]=x; s1+=x; s2+=x*x; }
    rA[r][tid&15]=s1; rB[r][tid&15]=s2;
  }
  __syncthreads();
  if (tid<16){
    float s1=0.f,s2=0.f;
    #pragma unroll
    for (int c=0;c<16;c++){ s1+=rA[tid][c]; s2+=rB[tid][c]; }
    float mu = s1*(1.f/CSd), var = s2*(1.f/CSd) - mu*mu;
    mv[tid][0]=mu; mv[tid][1]=rsqrtf(var+1e-5f);
  }
  __syncthreads();
  {
    float mu=mv[r][0], rs=mv[r][1];
    #pragma unroll
    for (int k2=0;k2<16;k2++) As[r][c0+k2] = (v[k2]-mu)*rs*gi_[c0+k2] + bi_[c0+k2];
  }
  __syncthreads();
  gemm_stage(As, Bs, W1, c1, true, tid);
  __syncthreads();
  gemm_stage(Bs, Cs, W2, c2, true, tid);
  __syncthreads();
  gemm_stage(Cs, Bs, W3, c3, false, tid);
  __syncthreads();
  // stage 4: LN(sc_new + tr3*mask)
  {
    float mk = mask[i0+r];
    float s1=0.f, s2=0.f;
    #pragma unroll
    for (int k2=0;k2<16;k2++){ float x = As[r][c0+k2] + Bs[r][c0+k2]*mk; v[k2]=x; s1+=x; s2+=x*x; }
    rA[r][tid&15]=s1; rB[r][tid&15]=s2;
  }
  __syncthreads();
  if (tid<16){
    float s1=0.f,s2=0.f;
    #pragma unroll
    for (int c=0;c<16;c++){ s1+=rA[tid][c]; s2+=rB[tid][c]; }
    float mu = s1*(1.f/CSd), var = s2*(1.f/CSd) - mu*mu;
    mv[tid][0]=mu; mv[tid][1]=rsqrtf(var+1e-5f);
  }
  __syncthreads();
  {
    float mu=mv[r][0], rs=mv[r][1];
    float* out = scb + (size_t)(i0+r)*CSd + c0;
    #pragma unroll
    for (int k2=0;k2<16;k2++){
      float o = (v[k2]-mu)*rs*gt_[c0+k2] + bt_[c0+k2];
      As[r][c0+k2] = o;
      out[k2] = o;
    }
  }
  __syncthreads();
  // stage 5: upd (192-thread k-split) + quat update
  if (tid < 192){
    int rr = tid/12, o = (tid%12)>>1, half = tid&1;
    float acc = half ? 0.f : bbb[o];
    int kb = half*128;
    for (int k2=kb; k2<kb+128; k2++) acc += As[rr][k2]*wbb[k2*6+o];
    u6p[rr][o][half] = acc;
  }
  __syncthreads();
  if (tid < 16){
    int gidx = i0 + tid;
    float uu[6];
    #pragma unroll
    for (int o=0;o<6;o++) uu[o] = u6p[tid][o][0] + u6p[tid][o][1];
    float bq = uu[0], cq = uu[1], dq = uu[2];
    float norm = sqrtf(1.f + bq*bq + cq*cq + dq*dq);
    float a = 1.f/norm, b_ = bq/norm, c_ = cq/norm, d_ = dq/norm;
    float dR[9];
    dR[0] = a*a + b_*b_ - c_*c_ - d_*d_; dR[1] = 2.f*(b_*c_ - a*d_); dR[2] = 2.f*(b_*d_ + a*c_);
    dR[3] = 2.f*(b_*c_ + a*d_); dR[4] = a*a - b_*b_ + c_*c_ - d_*d_; dR[5] = 2.f*(c_*d_ - a*b_);
    dR[6] = 2.f*(b_*d_ - a*c_); dR[7] = 2.f*(c_*d_ + a*b_); dR[8] = a*a - b_*b_ - c_*c_ + d_*d_;
    float mk = mask[gidx];
    float dt0 = uu[3]*mk, dt1 = uu[4]*mk, dt2 = uu[5]*mk;
    float Rm[9];
    #pragma unroll
    for (int ii=0; ii<9; ii++) Rm[ii] = R[gidx*9+ii];
    t[gidx*3]   += Rm[0]*dt0 + Rm[1]*dt1 + Rm[2]*dt2;
    t[gidx*3+1] += Rm[3]*dt0 + Rm[4]*dt1 + Rm[5]*dt2;
    t[gidx*3+2] += Rm[6]*dt0 + Rm[7]*dt1 + Rm[8]*dt2;
    #pragma unroll
    for (int ii=0; ii<3; ii++)
      #pragma unroll
      for (int jj=0; jj<3; jj++)
        R[gidx*9 + ii*3 + jj] = Rm[ii*3]*dR[jj] + Rm[ii*3+1]*dR[3+jj] + Rm[ii*3+2]*dR[6+jj];
  }
}

// ------------- final output write -------------
__global__ __launch_bounds__(256) void k_writeout(
    const float* __restrict__ sc, const float* __restrict__ R, const float* __restrict__ t,
    float* __restrict__ out){
  int idx = blockIdx.x*256 + threadIdx.x;
  if      (idx < 131072) out[idx] = sc[idx];
  else if (idx < 135680) out[idx] = R[idx-131072];
  else if (idx < 137216) out[idx] = t[idx-135680];
}

extern "C" void kernel_launch(void* const* d_in, const int* in_sizes, int n_in,
                              void* d_out, int out_size, void* d_ws, size_t ws_size,
                              hipStream_t stream){
  const float* s      = (const float*)d_in[0];
  const float* z      = (const float*)d_in[1];
  const float* mask   = (const float*)d_in[2];
  const float* ln_s_g = (const float*)d_in[3];
  const float* ln_s_b = (const float*)d_in[4];
  const float* ln_z_g = (const float*)d_in[5];
  const float* ln_z_b = (const float*)d_in[6];
  const float* w_init = (const float*)d_in[7];
  const float* b_init = (const float*)d_in[8];
  const float* ln_ipa_g = (const float*)d_in[9];
  const float* ln_ipa_b = (const float*)d_in[10];
  const float* ln_tr_g  = (const float*)d_in[11];
  const float* ln_tr_b  = (const float*)d_in[12];
  const float* wq = (const float*)d_in[13]; const float* bq = (const float*)d_in[14];
  const float* wk = (const float*)d_in[15]; const float* bk = (const float*)d_in[16];
  const float* wv = (const float*)d_in[17]; const float* bv = (const float*)d_in[18];
  const float* wqp = (const float*)d_in[19]; const float* bqp = (const float*)d_in[20];
  const float* wkp = (const float*)d_in[21]; const float* bkp = (const float*)d_in[22];
  const float* wvp = (const float*)d_in[23]; const float* bvp = (const float*)d_in[24];
  const float* wpb = (const float*)d_in[25];
  const float* head_w = (const float*)d_in[26];
  const float* wo = (const float*)d_in[27]; const float* bo = (const float*)d_in[28];
  const float* wt1 = (const float*)d_in[29]; const float* bt1 = (const float*)d_in[30];
  const float* wt2 = (const float*)d_in[31]; const float* bt2 = (const float*)d_in[32];
  const float* wt3 = (const float*)d_in[33]; const float* bt3 = (const float*)d_in[34];
  const float* wbb = (const float*)d_in[35]; const float* bbb = (const float*)d_in[36];

  float* W = (float*)d_ws;
  float* scb   = W + OFF_SC;
  __half*  pbb  = (__half*)(W + OFF_PB);
  float* Pb    = W + OFF_P;
  float* qnb   = W + OFF_QN;
  float* knb   = W + OFF_KN;
  __hip_bfloat16* a16hi = (__hip_bfloat16*)(W + OFF_A16);
  float* catb  = W + OFF_CAT;
  float* s0b   = W + OFF_S0;
  float* Rb    = W + OFF_R;
  float* tb    = W + OFF_T;
  float* gammab= W + OFF_GAMMA;
  float* maskb = W + OFF_MASKB;
  float* bcat  = W + OFF_BCAT;
  __hip_bfloat16* WinitP = (__hip_bfloat16*)(W + OFF_WINITP);
  __hip_bfloat16* Wt1P   = (__hip_bfloat16*)(W + OFF_WT1P);
  __hip_bfloat16* Wt2P   = (__hip_bfloat16*)(W + OFF_WT2P);
  __hip_bfloat16* Wt3P   = (__hip_bfloat16*)(W + OFF_WT3P);
  __hip_bfloat16* WoP    = (__hip_bfloat16*)(W + OFF_WOP);
  __hip_bfloat16* WcatP  = (__hip_bfloat16*)(W + OFF_WCATP);
  float* Qp = W + OFF_QP;
  __hip_bfloat16* Kp = (__hip_bfloat16*)(W + OFF_KP);
  __hip_bfloat16* Vp = (__hip_bfloat16*)(W + OFF_VP);
  __hip_bfloat16* znt = (__hip_bfloat16*)(W + OFF_ZNT);

  k_setup<<<9, 256, 0, stream>>>(bq,bk,bv,bqp,bkp,bvp, head_w, mask, bcat, gammab, maskb, Rb, tb);
  k_pack_cat<<<CSd*NPROJ/256, 256, 0, stream>>>(wq,wk,wv,wqp,wkp,wvp, WcatP);
  k_pack<<<256,  256, 0, stream>>>(w_init, CSd, CSd, WinitP);
  k_pack<<<1536, 256, 0, stream>>>(wo, CATd, CSd, WoP);
  k_pack<<<256,  256, 0, stream>>>(wt1, CSd, CSd, Wt1P);
  k_pack<<<256,  256, 0, stream>>>(wt2, CSd, CSd, Wt2P);
  k_pack<<<256,  256, 0, stream>>>(wt3, CSd, CSd, Wt3P);

  k_addln<<<Lq, 256, 0, stream>>>(s, nullptr, ln_s_g, ln_s_b, s0b);
  k_gemm_mfma<4><<<dim3(4,8), 256, 0, stream>>>(s0b, CSd, WinitP, CSd, b_init, scb, 0, nullptr);
  k_lnz_pb<<<Lq*Lq/64, 256, 0, stream>>>(z, ln_z_g, ln_z_b, wpb, pbb, znt);

  for (int it=0; it<8; ++it){
    k_gemm_mfma<2><<<dim3(36,8), 256, 0, stream>>>(scb, CSd, WcatP, NPROJ, bcat, Pb, 0, nullptr);
    k_packqkv<<<3072, 256, 0, stream>>>(Pb, Rb, tb, gammab, Qp, Kp, Vp, qnb, knb);
    k_attn<<<dim3(32,8), 256, 0, stream>>>(Qp, Kp, Vp, qnb, knb, pbb, maskb, gammab, Rb, tb,
                                           a16hi, catb);
    k_opair_mfma<<<Lq, 256, 0, stream>>>(a16hi, znt, catb);
    k_mega<<<32, 256, 0, stream>>>(scb, catb, WoP, bo, ln_ipa_g, ln_ipa_b,
                                   Wt1P, bt1, Wt2P, bt2, Wt3P, bt3,
                                   ln_tr_g, ln_tr_b, mask, wbb, bbb, Rb, tb);
  }
  k_writeout<<<536, 256, 0, stream>>>(scb, Rb, tb, (float*)d_out);
}